// Round 1
// baseline (120.185 us; speedup 1.0000x reference)
//
#include <hip/hip_runtime.h>

#define DEV __device__ __forceinline__

typedef unsigned short u16;
typedef unsigned int u32;
typedef float f32x4 __attribute__((ext_vector_type(4)));
typedef __bf16 b16x8 __attribute__((ext_vector_type(8)));
typedef u16 u16x8 __attribute__((ext_vector_type(8)));
typedef u16 u16x4 __attribute__((ext_vector_type(4)));

#define SCALE 0.08838834764831845f  // 1/sqrt(128)  (reference scales by sqrt(D), not sqrt(DH))

DEV u16 bfr(float x) {  // fp32 -> bf16 RNE
  u32 u = __builtin_bit_cast(u32, x);
  u32 r = u + 0x7fffu + ((u >> 16) & 1u);
  return (u16)(r >> 16);
}

DEV f32x4 mfma16(b16x8 a, b16x8 b, f32x4 c) {
  return __builtin_amdgcn_mfma_f32_16x16x32_bf16(a, b, c, 0, 0, 0);
}

DEV b16x8 bzero8() {
  b16x8 x;
#pragma unroll
  for (int i = 0; i < 8; ++i) x[i] = (__bf16)0.0f;
  return x;
}

// ---------------------------------------------------------------------------
// K1: fused QKV projection.  grid (64, 3), 256 threads.
// mode 0: qp fp32 + q_bf (pre-scaled); mode 1: k_bf; mode 2: vt (transposed).
// ---------------------------------------------------------------------------
__global__ __launch_bounds__(256) void k_proj(
    const float* __restrict__ Xq, const float* __restrict__ Xk, const float* __restrict__ Xv,
    const float* __restrict__ Wq, const float* __restrict__ Wk, const float* __restrict__ Wv,
    const float* __restrict__ bq, const float* __restrict__ bk, const float* __restrict__ bv,
    float* __restrict__ qp, u16* __restrict__ q_bf, u16* __restrict__ k_bf,
    u16* __restrict__ vt) {
  __shared__ u16 Xs[128 * 128];
  __shared__ u16 Ws[128 * 128];
  const int tid = threadIdx.x;
  const int mode = blockIdx.y;
  const float* X = (mode == 0) ? Xq : (mode == 1 ? Xk : Xv);
  const float* W = (mode == 0) ? Wq : (mode == 1 ? Wk : Wv);
  const float* bias = (mode == 0) ? bq : (mode == 1 ? bk : bv);
  const int row0 = blockIdx.x * 128;
  char* xb = (char*)Xs;
  char* wb = (char*)Ws;

  // stage X tile fp32->bf16, rows of 256B, XOR-swizzled (T2): byte ^= (row&7)<<4
#pragma unroll
  for (int i = 0; i < 8; ++i) {
    int s = tid + i * 256;  // 16B slot id (2048 slots)
    int row = s >> 4;
    int c0 = (s & 15) * 8;
    const float* src = X + (size_t)(row0 + row) * 128 + c0;
    float4 f0 = *(const float4*)src;
    float4 f1 = *(const float4*)(src + 4);
    u16x8 hv;
    hv[0] = bfr(f0.x); hv[1] = bfr(f0.y); hv[2] = bfr(f0.z); hv[3] = bfr(f0.w);
    hv[4] = bfr(f1.x); hv[5] = bfr(f1.y); hv[6] = bfr(f1.z); hv[7] = bfr(f1.w);
    *(u16x8*)(xb + ((s * 16) ^ ((row & 7) << 4))) = hv;
  }
  // stage W^T -> Ws[n][k] bf16 (swizzled) so B-fragments are contiguous 16B
#pragma unroll
  for (int i = 0; i < 16; ++i) {
    int vecid = i * 256 + tid;
    int kk = vecid >> 5;
    int n0 = (vecid & 31) * 4;
    float4 f = *(const float4*)(W + (size_t)kk * 128 + n0);
    float ff[4] = {f.x, f.y, f.z, f.w};
#pragma unroll
    for (int j = 0; j < 4; ++j) {
      int n = n0 + j;
      *(u16*)(wb + ((n * 256 + kk * 2) ^ ((n & 7) << 4))) = bfr(ff[j]);
    }
  }
  __syncthreads();

  const int lane = tid & 63, wid = tid >> 6;
  const int g = lane >> 4, c = lane & 15;
  const int wi = wid >> 1, wj = wid & 1;

  f32x4 acc[4][4];
#pragma unroll
  for (int a = 0; a < 4; ++a)
#pragma unroll
    for (int b2 = 0; b2 < 4; ++b2) acc[a][b2] = f32x4{0.f, 0.f, 0.f, 0.f};

#pragma unroll
  for (int kk = 0; kk < 4; ++kk) {
    b16x8 af[4], bfv[4];
#pragma unroll
    for (int t = 0; t < 4; ++t) {
      int row = wi * 64 + t * 16 + c;
      af[t] = *(const b16x8*)(xb + ((row * 256 + kk * 64 + g * 16) ^ ((row & 7) << 4)));
      int col = wj * 64 + t * 16 + c;
      bfv[t] = *(const b16x8*)(wb + ((col * 256 + kk * 64 + g * 16) ^ ((col & 7) << 4)));
    }
#pragma unroll
    for (int ti = 0; ti < 4; ++ti)
#pragma unroll
      for (int tj = 0; tj < 4; ++tj) acc[ti][tj] = mfma16(af[ti], bfv[tj], acc[ti][tj]);
  }

  // epilogue: C/D layout col=lane&15, row=(lane>>4)*4+reg  [guide m89]
#pragma unroll
  for (int tj = 0; tj < 4; ++tj) {
    int col = wj * 64 + tj * 16 + c;
    float bia = bias[col];
    int h = col >> 4, dh = col & 15;
#pragma unroll
    for (int ti = 0; ti < 4; ++ti) {
      int nbase = row0 + wi * 64 + ti * 16 + g * 4;
      f32x4 v4 = acc[ti][tj];
      if (mode == 2) {
        // vt[b][h][dh][n]: rows 4g..4g+3 are consecutive n -> packed 8B store
        u16x4 pk;
#pragma unroll
        for (int r = 0; r < 4; ++r) pk[r] = bfr(v4[r] + bia);
        int bb2 = nbase >> 11, n = nbase & 2047;
        *(u16x4*)(vt + ((((size_t)bb2 * 8 + h) * 16 + dh) << 11) + n) = pk;
      } else {
        u16* dst = (mode == 0) ? q_bf : k_bf;
        float sc = (mode == 0) ? SCALE : 1.0f;
#pragma unroll
        for (int r = 0; r < 4; ++r) {
          int rowg = nbase + r;
          float val = v4[r] + bia;
          if (mode == 0) qp[(size_t)rowg * 128 + col] = val;
          int bb2 = rowg >> 11, n = rowg & 2047;
          dst[((((size_t)bb2 * 8 + h) * 2048 + n) << 4) + dh] = bfr(val * sc);
        }
      }
    }
  }
}

// ---------------------------------------------------------------------------
// K2: flash attention per (b,h).  grid (NQ/64, B*H) = (32,32), 256 threads.
// 4 waves, each owns 16 q-rows.  K-tile = 128 keys.
// ---------------------------------------------------------------------------
__global__ __launch_bounds__(256) void k_attn(
    const u16* __restrict__ q_bf, const u16* __restrict__ k_bf, const u16* __restrict__ vt,
    const int* __restrict__ mask, float* __restrict__ o) {
  __shared__ u16 Ks[128 * 16];      // K tile, natural [key][dh]
  __shared__ u16 Vs[16 * 128];      // V^T tile [dh][key], swizzled
  __shared__ u16 Ps[4][16 * 128];   // per-wave P [q][key], swizzled
  __shared__ float Ms[128];         // mask addend per key
  const int tid = threadIdx.x, lane = tid & 63, wid = tid >> 6;
  const int g = lane >> 4, c = lane & 15;
  const int bh = blockIdx.y, b = bh >> 3, h = bh & 7;
  const int q0 = blockIdx.x * 64;

  // Q fragment: A row = lane&15, k(dh) = 8g+j; dh only 0..15 -> groups 2,3 zero
  b16x8 qf = bzero8();
  if (g < 2)
    qf = *(const b16x8*)(q_bf + (((size_t)bh * 2048 + q0 + wid * 16 + c) << 4) + g * 8);

  float m_run[4], l_run[4];
  f32x4 oacc = f32x4{0.f, 0.f, 0.f, 0.f};
#pragma unroll
  for (int r = 0; r < 4; ++r) { m_run[r] = -1e30f; l_run[r] = 0.f; }

  const u16* Kg = k_bf + (size_t)bh * 2048 * 16;
  const u16* Vg = vt + (size_t)bh * 16 * 2048;
  char* ksb = (char*)Ks;
  char* vsb = (char*)Vs;
  char* psb = (char*)(Ps[wid]);

  for (int kt = 0; kt < 16; ++kt) {
    __syncthreads();  // previous iteration's Ks/Vs/Ms reads done
    *(u16x8*)(ksb + tid * 16) = *(const u16x8*)(Kg + (size_t)kt * 2048 + tid * 8);
    {
      u16x8 vv = *(const u16x8*)(Vg + (size_t)(tid >> 4) * 2048 + kt * 128 + (tid & 15) * 8);
      *(u16x8*)(vsb + ((tid * 16) ^ (((tid >> 4) & 7) << 4))) = vv;
    }
    if (tid < 128) Ms[tid] = mask[b * 2048 + kt * 128 + tid] ? 0.f : -1e30f;
    __syncthreads();

    // S = (Q/sqrt(D)) K^T  — K-dim zero-padded 16->32 (same MFMA count)
    f32x4 s[8];
#pragma unroll
    for (int t = 0; t < 8; ++t) {
      b16x8 kf = bzero8();
      if (g < 2) kf = *(const b16x8*)(ksb + (t * 16 + c) * 32 + g * 16);
      s[t] = mfma16(qf, kf, f32x4{0.f, 0.f, 0.f, 0.f});
    }

    // online softmax; row q=(g*4+r), key col = t*16 + c
    float tmax[4] = {-1e30f, -1e30f, -1e30f, -1e30f};
#pragma unroll
    for (int t = 0; t < 8; ++t) {
      float ma = Ms[t * 16 + c];
#pragma unroll
      for (int r = 0; r < 4; ++r) {
        s[t][r] += ma;
        tmax[r] = fmaxf(tmax[r], s[t][r]);
      }
    }
#pragma unroll
    for (int off = 1; off < 16; off <<= 1)
#pragma unroll
      for (int r = 0; r < 4; ++r) tmax[r] = fmaxf(tmax[r], __shfl_xor(tmax[r], off));

    float alpha[4], rsum[4];
#pragma unroll
    for (int r = 0; r < 4; ++r) {
      float mnew = fmaxf(m_run[r], tmax[r]);
      alpha[r] = __expf(m_run[r] - mnew);
      m_run[r] = mnew;
      rsum[r] = 0.f;
    }
#pragma unroll
    for (int t = 0; t < 8; ++t)
#pragma unroll
      for (int r = 0; r < 4; ++r) {
        float p = __expf(s[t][r] - m_run[r]);
        s[t][r] = p;
        rsum[r] += p;
      }
#pragma unroll
    for (int off = 1; off < 16; off <<= 1)
#pragma unroll
      for (int r = 0; r < 4; ++r) rsum[r] += __shfl_xor(rsum[r], off);
#pragma unroll
    for (int r = 0; r < 4; ++r) {
      l_run[r] = l_run[r] * alpha[r] + rsum[r];
      oacc[r] *= alpha[r];
    }

    // P -> per-wave LDS (bf16, swizzled), then read back as PV A-fragments
#pragma unroll
    for (int t = 0; t < 8; ++t)
#pragma unroll
      for (int r = 0; r < 4; ++r) {
        int qrow = g * 4 + r;
        *(u16*)(psb + ((qrow * 256 + (t * 16 + c) * 2) ^ ((qrow & 7) << 4))) = bfr(s[t][r]);
      }

    // O += P V : A row=q (lane&15), k=keys; B col=dh (lane&15), k=keys
#pragma unroll
    for (int k2 = 0; k2 < 4; ++k2) {
      b16x8 pf = *(const b16x8*)(psb + ((c * 256 + k2 * 64 + g * 16) ^ ((c & 7) << 4)));
      b16x8 vf = *(const b16x8*)(vsb + ((c * 256 + k2 * 64 + g * 16) ^ ((c & 7) << 4)));
      oacc = mfma16(pf, vf, oacc);
    }
  }

#pragma unroll
  for (int r = 0; r < 4; ++r) {
    float inv = (l_run[r] > 0.f) ? 1.0f / l_run[r] : 0.f;
    o[(size_t)(b * 2048 + q0 + wid * 16 + g * 4 + r) * 128 + h * 16 + c] = oacc[r] * inv;
  }
}

// ---------------------------------------------------------------------------
// K3: LN1 over x = qp + o.  One wave per row.  grid 2048, 256 threads.
// ---------------------------------------------------------------------------
__global__ __launch_bounds__(256) void k_ln1(
    const float* __restrict__ qp, const float* __restrict__ o,
    const float* __restrict__ g1, const float* __restrict__ b1,
    float* __restrict__ out1f, u16* __restrict__ out1b) {
  const int lane = threadIdx.x & 63;
  const int row = blockIdx.x * 4 + (threadIdx.x >> 6);
  const size_t base = (size_t)row * 128 + lane * 2;
  float2 a = *(const float2*)(qp + base);
  float2 bb = *(const float2*)(o + base);
  float x0 = a.x + bb.x, x1 = a.y + bb.y;
  float sum = x0 + x1, sq = x0 * x0 + x1 * x1;
#pragma unroll
  for (int off = 1; off < 64; off <<= 1) {
    sum += __shfl_xor(sum, off);
    sq += __shfl_xor(sq, off);
  }
  float mu = sum * (1.f / 128.f);
  float rstd = rsqrtf(sq * (1.f / 128.f) - mu * mu + 1e-6f);
  float2 gg = *(const float2*)(g1 + lane * 2);
  float2 be = *(const float2*)(b1 + lane * 2);
  float y0 = (x0 - mu) * rstd * gg.x + be.x;
  float y1 = (x1 - mu) * rstd * gg.y + be.y;
  *(float2*)(out1f + base) = make_float2(y0, y1);
  *(u32*)(out1b + base) = (u32)bfr(y0) | ((u32)bfr(y1) << 16);
}

// ---------------------------------------------------------------------------
// K4: y = out1 + relu(out1 @ Wo + bo).  grid 64, 256 threads.
// ---------------------------------------------------------------------------
__global__ __launch_bounds__(256) void k_mlp(
    const u16* __restrict__ out1b, const float* __restrict__ out1f,
    const float* __restrict__ Wo, const float* __restrict__ bo, float* __restrict__ y) {
  __shared__ u16 Xs[128 * 128];
  __shared__ u16 Ws[128 * 128];
  const int tid = threadIdx.x;
  const int row0 = blockIdx.x * 128;
  char* xb = (char*)Xs;
  char* wb = (char*)Ws;
#pragma unroll
  for (int i = 0; i < 8; ++i) {
    int s = tid + i * 256;
    int row = s >> 4;
    u16x8 hv = *(const u16x8*)(out1b + (size_t)(row0 + row) * 128 + (s & 15) * 8);
    *(u16x8*)(xb + ((s * 16) ^ ((row & 7) << 4))) = hv;
  }
#pragma unroll
  for (int i = 0; i < 16; ++i) {
    int vecid = i * 256 + tid;
    int kk = vecid >> 5;
    int n0 = (vecid & 31) * 4;
    float4 f = *(const float4*)(Wo + (size_t)kk * 128 + n0);
    float ff[4] = {f.x, f.y, f.z, f.w};
#pragma unroll
    for (int j = 0; j < 4; ++j) {
      int n = n0 + j;
      *(u16*)(wb + ((n * 256 + kk * 2) ^ ((n & 7) << 4))) = bfr(ff[j]);
    }
  }
  __syncthreads();

  const int lane = tid & 63, wid = tid >> 6;
  const int g = lane >> 4, c = lane & 15;
  const int wi = wid >> 1, wj = wid & 1;

  f32x4 acc[4][4];
#pragma unroll
  for (int a = 0; a < 4; ++a)
#pragma unroll
    for (int b2 = 0; b2 < 4; ++b2) acc[a][b2] = f32x4{0.f, 0.f, 0.f, 0.f};

#pragma unroll
  for (int kk = 0; kk < 4; ++kk) {
    b16x8 af[4], bfv[4];
#pragma unroll
    for (int t = 0; t < 4; ++t) {
      int row = wi * 64 + t * 16 + c;
      af[t] = *(const b16x8*)(xb + ((row * 256 + kk * 64 + g * 16) ^ ((row & 7) << 4)));
      int col = wj * 64 + t * 16 + c;
      bfv[t] = *(const b16x8*)(wb + ((col * 256 + kk * 64 + g * 16) ^ ((col & 7) << 4)));
    }
#pragma unroll
    for (int ti = 0; ti < 4; ++ti)
#pragma unroll
      for (int tj = 0; tj < 4; ++tj) acc[ti][tj] = mfma16(af[ti], bfv[tj], acc[ti][tj]);
  }

#pragma unroll
  for (int tj = 0; tj < 4; ++tj) {
    int col = wj * 64 + tj * 16 + c;
    float bia = bo[col];
#pragma unroll
    for (int ti = 0; ti < 4; ++ti) {
#pragma unroll
      for (int r = 0; r < 4; ++r) {
        int rowg = row0 + wi * 64 + ti * 16 + g * 4 + r;
        float val = acc[ti][tj][r] + bia;
        val = fmaxf(val, 0.f) + out1f[(size_t)rowg * 128 + col];
        y[(size_t)rowg * 128 + col] = val;
      }
    }
  }
}

// ---------------------------------------------------------------------------
// K5: final LN2 -> d_out.  grid 2048, 256 threads.
// ---------------------------------------------------------------------------
__global__ __launch_bounds__(256) void k_ln2(
    const float* __restrict__ yv, const float* __restrict__ g2, const float* __restrict__ b2,
    float* __restrict__ out) {
  const int lane = threadIdx.x & 63;
  const int row = blockIdx.x * 4 + (threadIdx.x >> 6);
  const size_t base = (size_t)row * 128 + lane * 2;
  float2 a = *(const float2*)(yv + base);
  float x0 = a.x, x1 = a.y;
  float sum = x0 + x1, sq = x0 * x0 + x1 * x1;
#pragma unroll
  for (int off = 1; off < 64; off <<= 1) {
    sum += __shfl_xor(sum, off);
    sq += __shfl_xor(sq, off);
  }
  float mu = sum * (1.f / 128.f);
  float rstd = rsqrtf(sq * (1.f / 128.f) - mu * mu + 1e-6f);
  float2 gg = *(const float2*)(g2 + lane * 2);
  float2 be = *(const float2*)(b2 + lane * 2);
  *(float2*)(out + base) =
      make_float2((x0 - mu) * rstd * gg.x + be.x, (x1 - mu) * rstd * gg.y + be.y);
}

// ---------------------------------------------------------------------------
extern "C" void kernel_launch(void* const* d_in, const int* in_sizes, int n_in,
                              void* d_out, int out_size, void* d_ws, size_t ws_size,
                              hipStream_t stream) {
  const float* q = (const float*)d_in[0];
  const float* k = (const float*)d_in[1];
  const float* v = (const float*)d_in[2];
  const int* mask = (const int*)d_in[3];
  const float* Wq = (const float*)d_in[4];
  const float* bq = (const float*)d_in[5];
  const float* Wk = (const float*)d_in[6];
  const float* bk = (const float*)d_in[7];
  const float* Wv = (const float*)d_in[8];
  const float* bv = (const float*)d_in[9];
  const float* Wo = (const float*)d_in[10];
  const float* bo = (const float*)d_in[11];
  const float* g1 = (const float*)d_in[12];
  const float* b1 = (const float*)d_in[13];
  const float* g2 = (const float*)d_in[14];
  const float* b2 = (const float*)d_in[15];

  char* ws = (char*)d_ws;  // 24 MiB used
  float* qp = (float*)(ws + (0ull << 20));          // 4 MiB fp32 [8192][128]
  u16* q_bf = (u16*)(ws + (4ull << 20));            // 2 MiB [bh][n][16] (pre-scaled)
  u16* k_bf = (u16*)(ws + (6ull << 20));            // 2 MiB [bh][n][16]
  u16* vt = (u16*)(ws + (8ull << 20));              // 2 MiB [bh][16][n]
  float* o = (float*)(ws + (10ull << 20));          // 4 MiB [8192][128]
  float* out1f = (float*)(ws + (14ull << 20));      // 4 MiB
  u16* out1b = (u16*)(ws + (18ull << 20));          // 2 MiB
  float* yy = (float*)(ws + (20ull << 20));         // 4 MiB

  k_proj<<<dim3(64, 3), 256, 0, stream>>>(q, k, v, Wq, Wk, Wv, bq, bk, bv,
                                          qp, q_bf, k_bf, vt);
  k_attn<<<dim3(32, 32), 256, 0, stream>>>(q_bf, k_bf, vt, mask, o);
  k_ln1<<<2048, 256, 0, stream>>>(qp, o, g1, b1, out1f, out1b);
  k_mlp<<<64, 256, 0, stream>>>(out1b, out1f, Wo, bo, yy);
  k_ln2<<<2048, 256, 0, stream>>>(yy, g2, b2, (float*)d_out);
}

// Round 2
// 99.141 us; speedup vs baseline: 1.2123x; 1.2123x over previous
//
#include <hip/hip_runtime.h>

#define DEV __device__ __forceinline__

typedef unsigned short u16;
typedef unsigned int u32;
typedef float f32x4 __attribute__((ext_vector_type(4)));
typedef float f32x16 __attribute__((ext_vector_type(16)));
typedef __bf16 b16x8 __attribute__((ext_vector_type(8)));
typedef u16 u16x8 __attribute__((ext_vector_type(8)));
typedef u16 u16x4 __attribute__((ext_vector_type(4)));
typedef u32 u32x4 __attribute__((ext_vector_type(4)));

// 1/sqrt(D) * log2(e): QK^T logits directly in log2 units (exp -> v_exp_f32)
#define QSCALE (0.08838834764831845f * 1.44269504089f)

DEV u16 bfr(float x) {  // fp32 -> bf16 RNE
  u32 u = __builtin_bit_cast(u32, x);
  u32 r = u + 0x7fffu + ((u >> 16) & 1u);
  return (u16)(r >> 16);
}

DEV f32x4 mfma16(b16x8 a, b16x8 b, f32x4 c) {
  return __builtin_amdgcn_mfma_f32_16x16x32_bf16(a, b, c, 0, 0, 0);
}

DEV void plswap(u32& a, u32& b) {  // a' = [a.lo32lanes, b.lo32lanes]; b' = [a.hi, b.hi]
  asm volatile("v_permlane32_swap_b32 %0, %1" : "+v"(a), "+v"(b));
}

DEV void gll16(const void* g, void* l) {
  __builtin_amdgcn_global_load_lds((const __attribute__((address_space(1))) u32*)g,
                                   (__attribute__((address_space(3))) u32*)l, 16, 0, 0);
}
DEV void gll4(const void* g, void* l) {
  __builtin_amdgcn_global_load_lds((const __attribute__((address_space(1))) u32*)g,
                                   (__attribute__((address_space(3))) u32*)l, 4, 0, 0);
}

// ---------------------------------------------------------------------------
// K0: mask -> f32 addend (0 / -1e30).  grid 32, 256 threads.
// ---------------------------------------------------------------------------
__global__ __launch_bounds__(256) void k_maskf(const int* __restrict__ mask,
                                               float* __restrict__ mf) {
  int i = blockIdx.x * 256 + threadIdx.x;
  mf[i] = mask[i] ? 0.f : -1e30f;
}

// ---------------------------------------------------------------------------
// K1: fused QKV projection.  grid (64, 3), 256 threads.
// mode 0: qp fp32 + q_bf (pre-scaled by QSCALE); mode 1: k_bf; mode 2: vt.
// ---------------------------------------------------------------------------
__global__ __launch_bounds__(256) void k_proj(
    const float* __restrict__ Xq, const float* __restrict__ Xk, const float* __restrict__ Xv,
    const float* __restrict__ Wq, const float* __restrict__ Wk, const float* __restrict__ Wv,
    const float* __restrict__ bq, const float* __restrict__ bk, const float* __restrict__ bv,
    float* __restrict__ qp, u16* __restrict__ q_bf, u16* __restrict__ k_bf,
    u16* __restrict__ vt) {
  __shared__ __align__(16) u16 Xs[128 * 128];
  __shared__ __align__(16) u16 Ws[128 * 128];
  const int tid = threadIdx.x;
  const int mode = blockIdx.y;
  const float* X = (mode == 0) ? Xq : (mode == 1 ? Xk : Xv);
  const float* W = (mode == 0) ? Wq : (mode == 1 ? Wk : Wv);
  const float* bias = (mode == 0) ? bq : (mode == 1 ? bk : bv);
  const int row0 = blockIdx.x * 128;
  char* xb = (char*)Xs;
  char* wb = (char*)Ws;

#pragma unroll
  for (int i = 0; i < 8; ++i) {
    int s = tid + i * 256;
    int row = s >> 4;
    int c0 = (s & 15) * 8;
    const float* src = X + (size_t)(row0 + row) * 128 + c0;
    float4 f0 = *(const float4*)src;
    float4 f1 = *(const float4*)(src + 4);
    u16x8 hv;
    hv[0] = bfr(f0.x); hv[1] = bfr(f0.y); hv[2] = bfr(f0.z); hv[3] = bfr(f0.w);
    hv[4] = bfr(f1.x); hv[5] = bfr(f1.y); hv[6] = bfr(f1.z); hv[7] = bfr(f1.w);
    *(u16x8*)(xb + ((s * 16) ^ ((row & 7) << 4))) = hv;
  }
#pragma unroll
  for (int i = 0; i < 16; ++i) {
    int vecid = i * 256 + tid;
    int kk = vecid >> 5;
    int n0 = (vecid & 31) * 4;
    float4 f = *(const float4*)(W + (size_t)kk * 128 + n0);
    float ff[4] = {f.x, f.y, f.z, f.w};
#pragma unroll
    for (int j = 0; j < 4; ++j) {
      int n = n0 + j;
      *(u16*)(wb + ((n * 256 + kk * 2) ^ ((n & 7) << 4))) = bfr(ff[j]);
    }
  }
  __syncthreads();

  const int lane = tid & 63, wid = tid >> 6;
  const int g = lane >> 4, c = lane & 15;
  const int wi = wid >> 1, wj = wid & 1;

  f32x4 acc[4][4];
#pragma unroll
  for (int a = 0; a < 4; ++a)
#pragma unroll
    for (int b2 = 0; b2 < 4; ++b2) acc[a][b2] = f32x4{0.f, 0.f, 0.f, 0.f};

#pragma unroll
  for (int kk = 0; kk < 4; ++kk) {
    b16x8 af[4], bfv[4];
#pragma unroll
    for (int t = 0; t < 4; ++t) {
      int row = wi * 64 + t * 16 + c;
      af[t] = *(const b16x8*)(xb + ((row * 256 + kk * 64 + g * 16) ^ ((row & 7) << 4)));
      int col = wj * 64 + t * 16 + c;
      bfv[t] = *(const b16x8*)(wb + ((col * 256 + kk * 64 + g * 16) ^ ((col & 7) << 4)));
    }
#pragma unroll
    for (int ti = 0; ti < 4; ++ti)
#pragma unroll
      for (int tj = 0; tj < 4; ++tj) acc[ti][tj] = mfma16(af[ti], bfv[tj], acc[ti][tj]);
  }

#pragma unroll
  for (int tj = 0; tj < 4; ++tj) {
    int col = wj * 64 + tj * 16 + c;
    float bia = bias[col];
    int h = col >> 4, dh = col & 15;
#pragma unroll
    for (int ti = 0; ti < 4; ++ti) {
      int nbase = row0 + wi * 64 + ti * 16 + g * 4;
      f32x4 v4 = acc[ti][tj];
      if (mode == 2) {
        u16x4 pk;
#pragma unroll
        for (int r = 0; r < 4; ++r) pk[r] = bfr(v4[r] + bia);
        int bb2 = nbase >> 11, n = nbase & 2047;
        *(u16x4*)(vt + ((((size_t)bb2 * 8 + h) * 16 + dh) << 11) + n) = pk;
      } else {
        u16* dst = (mode == 0) ? q_bf : k_bf;
        float sc = (mode == 0) ? QSCALE : 1.0f;
#pragma unroll
        for (int r = 0; r < 4; ++r) {
          int rowg = nbase + r;
          float val = v4[r] + bia;
          if (mode == 0) qp[(size_t)rowg * 128 + col] = val;
          int bb2 = rowg >> 11, n = rowg & 2047;
          dst[((((size_t)bb2 * 8 + h) * 2048 + n) << 4) + dh] = bfr(val * sc);
        }
      }
    }
  }
}

// ---------------------------------------------------------------------------
// K2: flash attention, swapped-QK 32x32x16, in-register softmax (T12/T13).
// grid (NQ/128, B*H) = (16, 32), 256 threads (4 waves x 32 q-rows).
// ---------------------------------------------------------------------------
__global__ __launch_bounds__(256) void k_attn2(
    const u16* __restrict__ q_bf, const u16* __restrict__ k_bf,
    const u16* __restrict__ vt, const float* __restrict__ mf,
    float* __restrict__ o) {
  __shared__ __align__(16) u16 Ks[2][128 * 16];   // [key][dh] linear
  __shared__ __align__(16) u16 Vs[2][16 * 128];   // [dh][k], 16B-slot XOR(dh&7) swizzled
  __shared__ __align__(16) float Mf2[2][128];     // mask addends
  __shared__ __align__(16) float xbuf[4][32];     // per-wave broadcast scratch
  const int tid = threadIdx.x, lane = tid & 63, wid = tid >> 6;
  const int q = lane & 31, h = lane >> 5;
  const int bh = blockIdx.y, b = bh >> 3, hh = bh & 7;
  const int q0 = blockIdx.x * 128 + wid * 32;

  const u16* Kg = k_bf + (size_t)bh * 2048 * 16;
  const u16* Vg = vt + (size_t)bh * 16 * 2048;
  const float* Mg = mf + (size_t)b * 2048;

  // Q B-fragment (col=q, k=dh): held in regs for the whole kernel
  b16x8 qf = *(const b16x8*)(q_bf + (((size_t)bh * 2048 + q0 + q) << 4) + h * 8);

  f32x16 oacc = {};
  float m_run = -1e4f, l_run = 0.f;

  auto stage = [&](int bufi, int ct2) {
    const int kt0 = ct2 * 128;
    // K: 4KB contiguous; wave wid stages keys [kt0+32*wid, +32)
    gll16(Kg + (((size_t)(kt0 + wid * 32)) << 4) + lane * 8, &Ks[bufi][wid * 512]);
    // V: wave stages dh rows 4*wid..+3; source pre-swizzled so LDS-linear = swizzled layout
    {
      const int dhs = wid * 4 + (lane >> 4);
      const int ts = (lane & 15) ^ (dhs & 7);
      gll16(Vg + (size_t)dhs * 2048 + kt0 + ts * 8, &Vs[bufi][wid * 512]);
    }
    if (wid < 2) gll4(Mg + kt0 + wid * 64 + lane, &Mf2[bufi][wid * 64]);
  };

  stage(0, 0);

  for (int ct = 0; ct < 16; ++ct) {
    const int cur = ct & 1;
    __syncthreads();  // drains vmcnt: buf[cur] staged; all waves done reading buf[cur^1]
    if (ct < 15) stage(cur ^ 1, ct + 1);
    const u16* ksb = Ks[cur];
    const char* vsb = (const char*)Vs[cur];
    const float* mfb = Mf2[cur];

#pragma unroll
    for (int kt = 0; kt < 4; ++kt) {
      // S^T = mfma(A=K[32k x 16dh], B=Q[32q x 16dh]); lane: col=q, rows=keys
      b16x8 kf = *(const b16x8*)(ksb + (kt * 32 + q) * 16 + h * 8);
      f32x16 zz = {};
      f32x16 st = __builtin_amdgcn_mfma_f32_32x32x16_bf16(kf, qf, zz, 0, 0, 0);

      // mask addends for keys (r&3)+8*(r>>2)+4h  (4x f32x4 broadcast reads)
      const float* mrow = mfb + kt * 32 + 4 * h;
      f32x4 ma[4];
      ma[0] = *(const f32x4*)(mrow);
      ma[1] = *(const f32x4*)(mrow + 8);
      ma[2] = *(const f32x4*)(mrow + 16);
      ma[3] = *(const f32x4*)(mrow + 24);
      float s[16];
#pragma unroll
      for (int g2 = 0; g2 < 4; ++g2)
#pragma unroll
        for (int j = 0; j < 4; ++j) s[g2 * 4 + j] = st[g2 * 4 + j] + ma[g2][j];

      // per-q tile max: in-lane tree + cross-half permlane swap (order-symmetric)
      float pm = s[0];
#pragma unroll
      for (int r = 1; r < 16; ++r) pm = fmaxf(pm, s[r]);
      {
        u32 pa = __builtin_bit_cast(u32, pm), pb = pa;
        plswap(pa, pb);
        pm = fmaxf(__builtin_bit_cast(float, pa), __builtin_bit_cast(float, pb));
      }

      // T13 defer-max: rescale only when max grows > 8 (log2 units); uniform branch
      if (__any(pm - m_run > 8.0f)) {
        float mnew = fmaxf(m_run, pm);
        float al = exp2f(m_run - mnew);
        m_run = mnew;
        l_run *= al;
        if (lane < 32) xbuf[wid][q] = al;
        f32x4 av[4];
#pragma unroll
        for (int g2 = 0; g2 < 4; ++g2) av[g2] = *(const f32x4*)&xbuf[wid][g2 * 8 + 4 * h];
#pragma unroll
        for (int g2 = 0; g2 < 4; ++g2)
#pragma unroll
          for (int j = 0; j < 4; ++j) oacc[g2 * 4 + j] *= av[g2][j];
      }

      // p = 2^(s - m), row-sum
      float p[16];
      float rs = 0.f;
#pragma unroll
      for (int r = 0; r < 16; ++r) {
        p[r] = exp2f(s[r] - m_run);
        rs += p[r];
      }
      {
        u32 ra = __builtin_bit_cast(u32, rs), rb = ra;
        plswap(ra, rb);
        rs = __builtin_bit_cast(float, ra) + __builtin_bit_cast(float, rb);
      }
      l_run += rs;

      // T12: P -> bf16 PV A-fragments fully in-register
      u32 w[8];
#pragma unroll
      for (int i = 0; i < 8; ++i)
        asm("v_cvt_pk_bf16_f32 %0, %1, %2" : "=v"(w[i]) : "v"(p[2 * i]), "v"(p[2 * i + 1]));
      plswap(w[0], w[2]); plswap(w[1], w[3]);
      plswap(w[4], w[6]); plswap(w[5], w[7]);
      u32x4 f0v = {w[0], w[1], w[2], w[3]};
      u32x4 f1v = {w[4], w[5], w[6], w[7]};
      b16x8 F0 = __builtin_bit_cast(b16x8, f0v);
      b16x8 F1 = __builtin_bit_cast(b16x8, f1v);

      // V B-fragments (col=dh, k=key), swizzled slots
      const int dh = lane & 15;
      const int t0 = (kt * 4 + h) ^ (dh & 7);
      const int t1 = (kt * 4 + 2 + h) ^ (dh & 7);
      b16x8 vf0 = *(const b16x8*)(vsb + (dh * 16 + t0) * 16);
      b16x8 vf1 = *(const b16x8*)(vsb + (dh * 16 + t1) * 16);
      oacc = __builtin_amdgcn_mfma_f32_32x32x16_bf16(F0, vf0, oacc, 0, 0, 0);
      oacc = __builtin_amdgcn_mfma_f32_32x32x16_bf16(F1, vf1, oacc, 0, 0, 0);
    }
  }

  // epilogue: broadcast 1/l by q-row, write O (cols dh<16 valid)
  if (lane < 32) xbuf[wid][q] = (l_run > 0.f) ? 1.0f / l_run : 0.f;
  f32x4 iv[4];
#pragma unroll
  for (int g2 = 0; g2 < 4; ++g2) iv[g2] = *(const f32x4*)&xbuf[wid][g2 * 8 + 4 * h];
  if ((lane & 31) < 16) {
    const int dho = lane & 31;
#pragma unroll
    for (int g2 = 0; g2 < 4; ++g2)
#pragma unroll
      for (int j = 0; j < 4; ++j) {
        int row = j + 8 * g2 + 4 * h;
        o[((size_t)b * 2048 + q0 + row) * 128 + hh * 16 + dho] = oacc[g2 * 4 + j] * iv[g2][j];
      }
  }
}

// ---------------------------------------------------------------------------
// K3: LN1 over x = qp + o.  grid 2048, 256 threads.
// ---------------------------------------------------------------------------
__global__ __launch_bounds__(256) void k_ln1(
    const float* __restrict__ qp, const float* __restrict__ o,
    const float* __restrict__ g1, const float* __restrict__ b1,
    float* __restrict__ out1f, u16* __restrict__ out1b) {
  const int lane = threadIdx.x & 63;
  const int row = blockIdx.x * 4 + (threadIdx.x >> 6);
  const size_t base = (size_t)row * 128 + lane * 2;
  float2 a = *(const float2*)(qp + base);
  float2 bb = *(const float2*)(o + base);
  float x0 = a.x + bb.x, x1 = a.y + bb.y;
  float sum = x0 + x1, sq = x0 * x0 + x1 * x1;
#pragma unroll
  for (int off = 1; off < 64; off <<= 1) {
    sum += __shfl_xor(sum, off);
    sq += __shfl_xor(sq, off);
  }
  float mu = sum * (1.f / 128.f);
  float rstd = rsqrtf(sq * (1.f / 128.f) - mu * mu + 1e-6f);
  float2 gg = *(const float2*)(g1 + lane * 2);
  float2 be = *(const float2*)(b1 + lane * 2);
  float y0 = (x0 - mu) * rstd * gg.x + be.x;
  float y1 = (x1 - mu) * rstd * gg.y + be.y;
  *(float2*)(out1f + base) = make_float2(y0, y1);
  *(u32*)(out1b + base) = (u32)bfr(y0) | ((u32)bfr(y1) << 16);
}

// ---------------------------------------------------------------------------
// K4: y = out1 + relu(out1 @ Wo + bo).  grid 64, 256 threads.
// ---------------------------------------------------------------------------
__global__ __launch_bounds__(256) void k_mlp(
    const u16* __restrict__ out1b, const float* __restrict__ out1f,
    const float* __restrict__ Wo, const float* __restrict__ bo, float* __restrict__ y) {
  __shared__ __align__(16) u16 Xs[128 * 128];
  __shared__ __align__(16) u16 Ws[128 * 128];
  const int tid = threadIdx.x;
  const int row0 = blockIdx.x * 128;
  char* xb = (char*)Xs;
  char* wb = (char*)Ws;
#pragma unroll
  for (int i = 0; i < 8; ++i) {
    int s = tid + i * 256;
    int row = s >> 4;
    u16x8 hv = *(const u16x8*)(out1b + (size_t)(row0 + row) * 128 + (s & 15) * 8);
    *(u16x8*)(xb + ((s * 16) ^ ((row & 7) << 4))) = hv;
  }
#pragma unroll
  for (int i = 0; i < 16; ++i) {
    int vecid = i * 256 + tid;
    int kk = vecid >> 5;
    int n0 = (vecid & 31) * 4;
    float4 f = *(const float4*)(Wo + (size_t)kk * 128 + n0);
    float ff[4] = {f.x, f.y, f.z, f.w};
#pragma unroll
    for (int j = 0; j < 4; ++j) {
      int n = n0 + j;
      *(u16*)(wb + ((n * 256 + kk * 2) ^ ((n & 7) << 4))) = bfr(ff[j]);
    }
  }
  __syncthreads();

  const int lane = tid & 63, wid = tid >> 6;
  const int g = lane >> 4, c = lane & 15;
  const int wi = wid >> 1, wj = wid & 1;

  f32x4 acc[4][4];
#pragma unroll
  for (int a = 0; a < 4; ++a)
#pragma unroll
    for (int b2 = 0; b2 < 4; ++b2) acc[a][b2] = f32x4{0.f, 0.f, 0.f, 0.f};

#pragma unroll
  for (int kk = 0; kk < 4; ++kk) {
    b16x8 af[4], bfv[4];
#pragma unroll
    for (int t = 0; t < 4; ++t) {
      int row = wi * 64 + t * 16 + c;
      af[t] = *(const b16x8*)(xb + ((row * 256 + kk * 64 + g * 16) ^ ((row & 7) << 4)));
      int col = wj * 64 + t * 16 + c;
      bfv[t] = *(const b16x8*)(wb + ((col * 256 + kk * 64 + g * 16) ^ ((col & 7) << 4)));
    }
#pragma unroll
    for (int ti = 0; ti < 4; ++ti)
#pragma unroll
      for (int tj = 0; tj < 4; ++tj) acc[ti][tj] = mfma16(af[ti], bfv[tj], acc[ti][tj]);
  }

#pragma unroll
  for (int tj = 0; tj < 4; ++tj) {
    int col = wj * 64 + tj * 16 + c;
    float bia = bo[col];
#pragma unroll
    for (int ti = 0; ti < 4; ++ti) {
#pragma unroll
      for (int r = 0; r < 4; ++r) {
        int rowg = row0 + wi * 64 + ti * 16 + g * 4 + r;
        float val = acc[ti][tj][r] + bia;
        val = fmaxf(val, 0.f) + out1f[(size_t)rowg * 128 + col];
        y[(size_t)rowg * 128 + col] = val;
      }
    }
  }
}

// ---------------------------------------------------------------------------
// K5: final LN2 -> d_out.  grid 2048, 256 threads.
// ---------------------------------------------------------------------------
__global__ __launch_bounds__(256) void k_ln2(
    const float* __restrict__ yv, const float* __restrict__ g2, const float* __restrict__ b2,
    float* __restrict__ out) {
  const int lane = threadIdx.x & 63;
  const int row = blockIdx.x * 4 + (threadIdx.x >> 6);
  const size_t base = (size_t)row * 128 + lane * 2;
  float2 a = *(const float2*)(yv + base);
  float x0 = a.x, x1 = a.y;
  float sum = x0 + x1, sq = x0 * x0 + x1 * x1;
#pragma unroll
  for (int off = 1; off < 64; off <<= 1) {
    sum += __shfl_xor(sum, off);
    sq += __shfl_xor(sq, off);
  }
  float mu = sum * (1.f / 128.f);
  float rstd = rsqrtf(sq * (1.f / 128.f) - mu * mu + 1e-6f);
  float2 gg = *(const float2*)(g2 + lane * 2);
  float2 be = *(const float2*)(b2 + lane * 2);
  *(float2*)(out + base) =
      make_float2((x0 - mu) * rstd * gg.x + be.x, (x1 - mu) * rstd * gg.y + be.y);
}

// ---------------------------------------------------------------------------
extern "C" void kernel_launch(void* const* d_in, const int* in_sizes, int n_in,
                              void* d_out, int out_size, void* d_ws, size_t ws_size,
                              hipStream_t stream) {
  const float* q = (const float*)d_in[0];
  const float* k = (const float*)d_in[1];
  const float* v = (const float*)d_in[2];
  const int* mask = (const int*)d_in[3];
  const float* Wq = (const float*)d_in[4];
  const float* bq = (const float*)d_in[5];
  const float* Wk = (const float*)d_in[6];
  const float* bk = (const float*)d_in[7];
  const float* Wv = (const float*)d_in[8];
  const float* bv = (const float*)d_in[9];
  const float* Wo = (const float*)d_in[10];
  const float* bo = (const float*)d_in[11];
  const float* g1 = (const float*)d_in[12];
  const float* b1 = (const float*)d_in[13];
  const float* g2 = (const float*)d_in[14];
  const float* b2 = (const float*)d_in[15];

  char* ws = (char*)d_ws;
  float* qp = (float*)(ws + (0ull << 20));      // 4 MiB fp32 [8192][128]
  u16* q_bf = (u16*)(ws + (4ull << 20));        // 2 MiB [bh][n][16] (pre-scaled, log2e folded)
  u16* k_bf = (u16*)(ws + (6ull << 20));        // 2 MiB [bh][n][16]
  u16* vt = (u16*)(ws + (8ull << 20));          // 2 MiB [bh][16][n]
  float* o = (float*)(ws + (10ull << 20));      // 4 MiB [8192][128]
  float* out1f = (float*)(ws + (14ull << 20));  // 4 MiB
  u16* out1b = (u16*)(ws + (18ull << 20));      // 2 MiB
  float* yy = (float*)(ws + (20ull << 20));     // 4 MiB
  float* mf = (float*)(ws + (24ull << 20));     // 32 KiB mask addends [B][2048]

  k_maskf<<<32, 256, 0, stream>>>(mask, mf);
  k_proj<<<dim3(64, 3), 256, 0, stream>>>(q, k, v, Wq, Wk, Wv, bq, bk, bv,
                                          qp, q_bf, k_bf, vt);
  k_attn2<<<dim3(16, 32), 256, 0, stream>>>(q_bf, k_bf, vt, mf, o);
  k_ln1<<<2048, 256, 0, stream>>>(qp, o, g1, b1, out1f, out1b);
  k_mlp<<<64, 256, 0, stream>>>(out1b, out1f, Wo, bo, yy);
  k_ln2<<<2048, 256, 0, stream>>>(yy, g2, b2, (float*)d_out);
}

// Round 3
// 88.334 us; speedup vs baseline: 1.3606x; 1.1223x over previous
//
#include <hip/hip_runtime.h>

#define DEV __device__ __forceinline__

typedef unsigned short u16;
typedef unsigned int u32;
typedef float f32x4 __attribute__((ext_vector_type(4)));
typedef float f32x16 __attribute__((ext_vector_type(16)));
typedef __bf16 b16x8 __attribute__((ext_vector_type(8)));
typedef u16 u16x8 __attribute__((ext_vector_type(8)));
typedef u16 u16x4 __attribute__((ext_vector_type(4)));
typedef u32 u32x4 __attribute__((ext_vector_type(4)));

// 1/sqrt(D) * log2(e): QK^T logits directly in log2 units (exp -> v_exp_f32)
#define QSCALE (0.08838834764831845f * 1.44269504089f)

DEV u16 bfr(float x) {  // fp32 -> bf16 RNE
  u32 u = __builtin_bit_cast(u32, x);
  u32 r = u + 0x7fffu + ((u >> 16) & 1u);
  return (u16)(r >> 16);
}

DEV f32x4 mfma16(b16x8 a, b16x8 b, f32x4 c) {
  return __builtin_amdgcn_mfma_f32_16x16x32_bf16(a, b, c, 0, 0, 0);
}

DEV void plswap(u32& a, u32& b) {  // a' = [a.lo32lanes, b.lo32lanes]; b' = [a.hi, b.hi]
  asm volatile("v_permlane32_swap_b32 %0, %1" : "+v"(a), "+v"(b));
}

DEV void gll16(const void* g, void* l) {
  __builtin_amdgcn_global_load_lds((const __attribute__((address_space(1))) u32*)g,
                                   (__attribute__((address_space(3))) u32*)l, 16, 0, 0);
}
DEV void gll4(const void* g, void* l) {
  __builtin_amdgcn_global_load_lds((const __attribute__((address_space(1))) u32*)g,
                                   (__attribute__((address_space(3))) u32*)l, 4, 0, 0);
}

// ---------------------------------------------------------------------------
// K0: mask -> f32 addend (0 / -1e30).  grid 32, 256 threads.
// ---------------------------------------------------------------------------
__global__ __launch_bounds__(256) void k_maskf(const int* __restrict__ mask,
                                               float* __restrict__ mf) {
  int i = blockIdx.x * 256 + threadIdx.x;
  mf[i] = mask[i] ? 0.f : -1e30f;
}

// ---------------------------------------------------------------------------
// K1: fused QKV projection.  grid (64, 3), 256 threads.
// mode 0: qp fp32 + q_bf (pre-scaled by QSCALE); mode 1: k_bf; mode 2: vt.
// ---------------------------------------------------------------------------
__global__ __launch_bounds__(256) void k_proj(
    const float* __restrict__ Xq, const float* __restrict__ Xk, const float* __restrict__ Xv,
    const float* __restrict__ Wq, const float* __restrict__ Wk, const float* __restrict__ Wv,
    const float* __restrict__ bq, const float* __restrict__ bk, const float* __restrict__ bv,
    float* __restrict__ qp, u16* __restrict__ q_bf, u16* __restrict__ k_bf,
    u16* __restrict__ vt) {
  __shared__ __align__(16) u16 Xs[128 * 128];
  __shared__ __align__(16) u16 Ws[128 * 128];
  const int tid = threadIdx.x;
  const int mode = blockIdx.y;
  const float* X = (mode == 0) ? Xq : (mode == 1 ? Xk : Xv);
  const float* W = (mode == 0) ? Wq : (mode == 1 ? Wk : Wv);
  const float* bias = (mode == 0) ? bq : (mode == 1 ? bk : bv);
  const int row0 = blockIdx.x * 128;
  char* xb = (char*)Xs;
  char* wb = (char*)Ws;

#pragma unroll
  for (int i = 0; i < 8; ++i) {
    int s = tid + i * 256;
    int row = s >> 4;
    int c0 = (s & 15) * 8;
    const float* src = X + (size_t)(row0 + row) * 128 + c0;
    float4 f0 = *(const float4*)src;
    float4 f1 = *(const float4*)(src + 4);
    u16x8 hv;
    hv[0] = bfr(f0.x); hv[1] = bfr(f0.y); hv[2] = bfr(f0.z); hv[3] = bfr(f0.w);
    hv[4] = bfr(f1.x); hv[5] = bfr(f1.y); hv[6] = bfr(f1.z); hv[7] = bfr(f1.w);
    *(u16x8*)(xb + ((s * 16) ^ ((row & 7) << 4))) = hv;
  }
#pragma unroll
  for (int i = 0; i < 16; ++i) {
    int vecid = i * 256 + tid;
    int kk = vecid >> 5;
    int n0 = (vecid & 31) * 4;
    float4 f = *(const float4*)(W + (size_t)kk * 128 + n0);
    float ff[4] = {f.x, f.y, f.z, f.w};
#pragma unroll
    for (int j = 0; j < 4; ++j) {
      int n = n0 + j;
      *(u16*)(wb + ((n * 256 + kk * 2) ^ ((n & 7) << 4))) = bfr(ff[j]);
    }
  }
  __syncthreads();

  const int lane = tid & 63, wid = tid >> 6;
  const int g = lane >> 4, c = lane & 15;
  const int wi = wid >> 1, wj = wid & 1;

  f32x4 acc[4][4];
#pragma unroll
  for (int a = 0; a < 4; ++a)
#pragma unroll
    for (int b2 = 0; b2 < 4; ++b2) acc[a][b2] = f32x4{0.f, 0.f, 0.f, 0.f};

#pragma unroll
  for (int kk = 0; kk < 4; ++kk) {
    b16x8 af[4], bfv[4];
#pragma unroll
    for (int t = 0; t < 4; ++t) {
      int row = wi * 64 + t * 16 + c;
      af[t] = *(const b16x8*)(xb + ((row * 256 + kk * 64 + g * 16) ^ ((row & 7) << 4)));
      int col = wj * 64 + t * 16 + c;
      bfv[t] = *(const b16x8*)(wb + ((col * 256 + kk * 64 + g * 16) ^ ((col & 7) << 4)));
    }
#pragma unroll
    for (int ti = 0; ti < 4; ++ti)
#pragma unroll
      for (int tj = 0; tj < 4; ++tj) acc[ti][tj] = mfma16(af[ti], bfv[tj], acc[ti][tj]);
  }

#pragma unroll
  for (int tj = 0; tj < 4; ++tj) {
    int col = wj * 64 + tj * 16 + c;
    float bia = bias[col];
    int h = col >> 4, dh = col & 15;
#pragma unroll
    for (int ti = 0; ti < 4; ++ti) {
      int nbase = row0 + wi * 64 + ti * 16 + g * 4;
      f32x4 v4 = acc[ti][tj];
      if (mode == 2) {
        u16x4 pk;
#pragma unroll
        for (int r = 0; r < 4; ++r) pk[r] = bfr(v4[r] + bia);
        int bb2 = nbase >> 11, n = nbase & 2047;
        *(u16x4*)(vt + ((((size_t)bb2 * 8 + h) * 16 + dh) << 11) + n) = pk;
      } else {
        u16* dst = (mode == 0) ? q_bf : k_bf;
        float sc = (mode == 0) ? QSCALE : 1.0f;
#pragma unroll
        for (int r = 0; r < 4; ++r) {
          int rowg = nbase + r;
          float val = v4[r] + bia;
          if (mode == 0) qp[(size_t)rowg * 128 + col] = val;
          int bb2 = rowg >> 11, n = rowg & 2047;
          dst[((((size_t)bb2 * 8 + h) * 2048 + n) << 4) + dh] = bfr(val * sc);
        }
      }
    }
  }
}

// ---------------------------------------------------------------------------
// K2: flash attention, swapped-QK 32x32x16, fixed-max softmax, MFMA row-sum.
// grid (NQ/128, B*H, SPLIT=2), 256 threads (4 waves x 32 q-rows).
// Writes un-normalized O partials + l partials; combine fused into k_ln1.
// ---------------------------------------------------------------------------
__global__ __launch_bounds__(256) void k_attn3(
    const u16* __restrict__ q_bf, const u16* __restrict__ k_bf,
    const u16* __restrict__ vt, const float* __restrict__ mf,
    float* __restrict__ Opart, float* __restrict__ Lpart) {
  __shared__ __align__(16) u16 Ks[2][128 * 16];    // [key][dh] linear
  __shared__ __align__(16) u16 Vs[2][17 * 128];    // [dh][k] swizzled + ones row at dh=16
  __shared__ __align__(16) float Mf2[2][128];      // mask addends
  const int tid = threadIdx.x, lane = tid & 63, wid = tid >> 6;
  const int q = lane & 31, h = lane >> 5;
  const int bh = blockIdx.y, b = bh >> 3;
  const int z = blockIdx.z;
  const int q0 = blockIdx.x * 128 + wid * 32;

  const u16* Kg = k_bf + (size_t)bh * 2048 * 16;
  const u16* Vg = vt + (size_t)bh * 16 * 2048;
  const float* Mg = mf + (size_t)b * 2048;

  // Q B-fragment (col=q, k=dh): in regs all kernel
  b16x8 qf = *(const b16x8*)(q_bf + (((size_t)bh * 2048 + q0 + q) << 4) + h * 8);

  // ones rows (dh=16) for both buffers: rowsum-by-MFMA column
  if (tid < 32) {
    u16x8 ov;
#pragma unroll
    for (int i = 0; i < 8; ++i) ov[i] = 0x3F80;  // bf16 1.0
    *(u16x8*)(&Vs[tid >> 4][16 * 128 + (tid & 15) * 8]) = ov;
  }

  f32x16 oacc = {};

  auto stage = [&](int bufi, int ct2) {
    const int kt0 = ct2 * 128;
    gll16(Kg + (((size_t)(kt0 + wid * 32)) << 4) + lane * 8, &Ks[bufi][wid * 512]);
    {
      const int dhs = wid * 4 + (lane >> 4);
      const int ts = (lane & 15) ^ (dhs & 7);
      gll16(Vg + (size_t)dhs * 2048 + kt0 + ts * 8, &Vs[bufi][wid * 512]);
    }
    if (wid < 2) gll4(Mg + kt0 + wid * 64 + lane, &Mf2[bufi][wid * 64]);
  };

  const int ct0 = z * 8;
  stage(0, ct0);
  const int dhc = (q < 16) ? q : 16;  // V col: dh, clamped to ones row

  for (int ct = ct0; ct < ct0 + 8; ++ct) {
    const int cur = ct & 1;
    __syncthreads();
    if (ct < ct0 + 7) stage(cur ^ 1, ct + 1);
    const u16* ksb = Ks[cur];
    const char* vsb = (const char*)Vs[cur];
    const float* mfb = Mf2[cur];

#pragma unroll
    for (int kt = 0; kt < 4; ++kt) {
      // S^T = mfma(A=K[32k x 16dh], B=Q[32q x 16dh]); lane: col=q, rows=keys
      b16x8 kf = *(const b16x8*)(ksb + (kt * 32 + q) * 16 + h * 8);
      f32x16 zz = {};
      f32x16 st = __builtin_amdgcn_mfma_f32_32x32x16_bf16(kf, qf, zz, 0, 0, 0);

      // mask addends for keys (r&3)+8*(r>>2)+4h
      const float* mrow = mfb + kt * 32 + 4 * h;
      f32x4 ma[4];
      ma[0] = *(const f32x4*)(mrow);
      ma[1] = *(const f32x4*)(mrow + 8);
      ma[2] = *(const f32x4*)(mrow + 16);
      ma[3] = *(const f32x4*)(mrow + 24);

      // fixed-max softmax: p = 2^(s + mask); masked -> exp2(-1e30) = 0
      float p[16];
#pragma unroll
      for (int g2 = 0; g2 < 4; ++g2)
#pragma unroll
        for (int j = 0; j < 4; ++j) p[g2 * 4 + j] = exp2f(st[g2 * 4 + j] + ma[g2][j]);

      // T12: P -> bf16 PV A-fragments in-register
      u32 w[8];
#pragma unroll
      for (int i = 0; i < 8; ++i)
        asm("v_cvt_pk_bf16_f32 %0, %1, %2" : "=v"(w[i]) : "v"(p[2 * i]), "v"(p[2 * i + 1]));
      plswap(w[0], w[2]); plswap(w[1], w[3]);
      plswap(w[4], w[6]); plswap(w[5], w[7]);
      u32x4 f0v = {w[0], w[1], w[2], w[3]};
      u32x4 f1v = {w[4], w[5], w[6], w[7]};
      b16x8 F0 = __builtin_bit_cast(b16x8, f0v);
      b16x8 F1 = __builtin_bit_cast(b16x8, f1v);

      // V B-fragments (col=dh or ones row), swizzled slots
      const int t0 = (kt * 4 + h) ^ (dhc & 7);
      const int t1 = (kt * 4 + 2 + h) ^ (dhc & 7);
      b16x8 vf0 = *(const b16x8*)(vsb + (dhc * 16 + t0) * 16);
      b16x8 vf1 = *(const b16x8*)(vsb + (dhc * 16 + t1) * 16);
      oacc = __builtin_amdgcn_mfma_f32_32x32x16_bf16(F0, vf0, oacc, 0, 0, 0);
      oacc = __builtin_amdgcn_mfma_f32_32x32x16_bf16(F1, vf1, oacc, 0, 0, 0);
    }
  }

  // epilogue: cols 0-15 = un-normalized O; col 16 = l (rowsum of P)
  const size_t rowbase = (size_t)(z * 32 + bh) * 2048 + q0;
  if (q < 16) {
    float* op = Opart + rowbase * 16 + q;
#pragma unroll
    for (int g2 = 0; g2 < 4; ++g2)
#pragma unroll
      for (int j = 0; j < 4; ++j) {
        int row = j + 8 * g2 + 4 * h;
        op[(size_t)row * 16] = oacc[g2 * 4 + j];
      }
  } else if (q == 16) {
    float* lp = Lpart + rowbase;
#pragma unroll
    for (int r = 0; r < 16; ++r) {
      int row = (r & 3) + 8 * (r >> 2) + 4 * h;
      lp[row] = oacc[r];
    }
  }
}

// ---------------------------------------------------------------------------
// K3: combine O partials + LN1 over x = qp + o.  grid 2048, 256 threads.
// ---------------------------------------------------------------------------
__global__ __launch_bounds__(256) void k_ln1(
    const float* __restrict__ qp, const float* __restrict__ Opart,
    const float* __restrict__ Lpart,
    const float* __restrict__ g1, const float* __restrict__ b1,
    float* __restrict__ out1f, u16* __restrict__ out1b) {
  const int lane = threadIdx.x & 63;
  const int row = blockIdx.x * 4 + (threadIdx.x >> 6);
  const int b = row >> 11, q = row & 2047;
  const int head = lane >> 3;        // col pair c0 = lane*2; head = c0>>4
  const int dh = (lane & 7) * 2;
  const size_t pb = (size_t)(b * 8 + head) * 2048 + q;
  const size_t SPLIT_O = (size_t)32 * 2048 * 16;
  const size_t SPLIT_L = (size_t)32 * 2048;
  float2 o0 = *(const float2*)(Opart + pb * 16 + dh);
  float2 o1 = *(const float2*)(Opart + SPLIT_O + pb * 16 + dh);
  float l = Lpart[pb] + Lpart[SPLIT_L + pb];
  float inv = (l > 0.f) ? 1.0f / l : 0.f;
  float ox = (o0.x + o1.x) * inv, oy = (o0.y + o1.y) * inv;

  const size_t base = (size_t)row * 128 + lane * 2;
  float2 a = *(const float2*)(qp + base);
  float x0 = a.x + ox, x1 = a.y + oy;
  float sum = x0 + x1, sq = x0 * x0 + x1 * x1;
#pragma unroll
  for (int off = 1; off < 64; off <<= 1) {
    sum += __shfl_xor(sum, off);
    sq += __shfl_xor(sq, off);
  }
  float mu = sum * (1.f / 128.f);
  float rstd = rsqrtf(sq * (1.f / 128.f) - mu * mu + 1e-6f);
  float2 gg = *(const float2*)(g1 + lane * 2);
  float2 be = *(const float2*)(b1 + lane * 2);
  float y0 = (x0 - mu) * rstd * gg.x + be.x;
  float y1 = (x1 - mu) * rstd * gg.y + be.y;
  *(float2*)(out1f + base) = make_float2(y0, y1);
  *(u32*)(out1b + base) = (u32)bfr(y0) | ((u32)bfr(y1) << 16);
}

// ---------------------------------------------------------------------------
// K4: y = out1 + relu(out1 @ Wo + bo).  grid 64, 256 threads.
// ---------------------------------------------------------------------------
__global__ __launch_bounds__(256) void k_mlp(
    const u16* __restrict__ out1b, const float* __restrict__ out1f,
    const float* __restrict__ Wo, const float* __restrict__ bo, float* __restrict__ y) {
  __shared__ __align__(16) u16 Xs[128 * 128];
  __shared__ __align__(16) u16 Ws[128 * 128];
  const int tid = threadIdx.x;
  const int row0 = blockIdx.x * 128;
  char* xb = (char*)Xs;
  char* wb = (char*)Ws;
#pragma unroll
  for (int i = 0; i < 8; ++i) {
    int s = tid + i * 256;
    int row = s >> 4;
    u16x8 hv = *(const u16x8*)(out1b + (size_t)(row0 + row) * 128 + (s & 15) * 8);
    *(u16x8*)(xb + ((s * 16) ^ ((row & 7) << 4))) = hv;
  }
#pragma unroll
  for (int i = 0; i < 16; ++i) {
    int vecid = i * 256 + tid;
    int kk = vecid >> 5;
    int n0 = (vecid & 31) * 4;
    float4 f = *(const float4*)(Wo + (size_t)kk * 128 + n0);
    float ff[4] = {f.x, f.y, f.z, f.w};
#pragma unroll
    for (int j = 0; j < 4; ++j) {
      int n = n0 + j;
      *(u16*)(wb + ((n * 256 + kk * 2) ^ ((n & 7) << 4))) = bfr(ff[j]);
    }
  }
  __syncthreads();

  const int lane = tid & 63, wid = tid >> 6;
  const int g = lane >> 4, c = lane & 15;
  const int wi = wid >> 1, wj = wid & 1;

  f32x4 acc[4][4];
#pragma unroll
  for (int a = 0; a < 4; ++a)
#pragma unroll
    for (int b2 = 0; b2 < 4; ++b2) acc[a][b2] = f32x4{0.f, 0.f, 0.f, 0.f};

#pragma unroll
  for (int kk = 0; kk < 4; ++kk) {
    b16x8 af[4], bfv[4];
#pragma unroll
    for (int t = 0; t < 4; ++t) {
      int row = wi * 64 + t * 16 + c;
      af[t] = *(const b16x8*)(xb + ((row * 256 + kk * 64 + g * 16) ^ ((row & 7) << 4)));
      int col = wj * 64 + t * 16 + c;
      bfv[t] = *(const b16x8*)(wb + ((col * 256 + kk * 64 + g * 16) ^ ((col & 7) << 4)));
    }
#pragma unroll
    for (int ti = 0; ti < 4; ++ti)
#pragma unroll
      for (int tj = 0; tj < 4; ++tj) acc[ti][tj] = mfma16(af[ti], bfv[tj], acc[ti][tj]);
  }

#pragma unroll
  for (int tj = 0; tj < 4; ++tj) {
    int col = wj * 64 + tj * 16 + c;
    float bia = bo[col];
#pragma unroll
    for (int ti = 0; ti < 4; ++ti) {
#pragma unroll
      for (int r = 0; r < 4; ++r) {
        int rowg = row0 + wi * 64 + ti * 16 + g * 4 + r;
        float val = acc[ti][tj][r] + bia;
        val = fmaxf(val, 0.f) + out1f[(size_t)rowg * 128 + col];
        y[(size_t)rowg * 128 + col] = val;
      }
    }
  }
}

// ---------------------------------------------------------------------------
// K5: final LN2 -> d_out.  grid 2048, 256 threads.
// ---------------------------------------------------------------------------
__global__ __launch_bounds__(256) void k_ln2(
    const float* __restrict__ yv, const float* __restrict__ g2, const float* __restrict__ b2,
    float* __restrict__ out) {
  const int lane = threadIdx.x & 63;
  const int row = blockIdx.x * 4 + (threadIdx.x >> 6);
  const size_t base = (size_t)row * 128 + lane * 2;
  float2 a = *(const float2*)(yv + base);
  float x0 = a.x, x1 = a.y;
  float sum = x0 + x1, sq = x0 * x0 + x1 * x1;
#pragma unroll
  for (int off = 1; off < 64; off <<= 1) {
    sum += __shfl_xor(sum, off);
    sq += __shfl_xor(sq, off);
  }
  float mu = sum * (1.f / 128.f);
  float rstd = rsqrtf(sq * (1.f / 128.f) - mu * mu + 1e-6f);
  float2 gg = *(const float2*)(g2 + lane * 2);
  float2 be = *(const float2*)(b2 + lane * 2);
  *(float2*)(out + base) =
      make_float2((x0 - mu) * rstd * gg.x + be.x, (x1 - mu) * rstd * gg.y + be.y);
}

// ---------------------------------------------------------------------------
extern "C" void kernel_launch(void* const* d_in, const int* in_sizes, int n_in,
                              void* d_out, int out_size, void* d_ws, size_t ws_size,
                              hipStream_t stream) {
  const float* q = (const float*)d_in[0];
  const float* k = (const float*)d_in[1];
  const float* v = (const float*)d_in[2];
  const int* mask = (const int*)d_in[3];
  const float* Wq = (const float*)d_in[4];
  const float* bq = (const float*)d_in[5];
  const float* Wk = (const float*)d_in[6];
  const float* bk = (const float*)d_in[7];
  const float* Wv = (const float*)d_in[8];
  const float* bv = (const float*)d_in[9];
  const float* Wo = (const float*)d_in[10];
  const float* bo = (const float*)d_in[11];
  const float* g1 = (const float*)d_in[12];
  const float* b1 = (const float*)d_in[13];
  const float* g2 = (const float*)d_in[14];
  const float* b2 = (const float*)d_in[15];

  // ws layout (19 MiB, lifetime-overlapped):
  char* ws = (char*)d_ws;
  float* qp = (float*)(ws + (0ull << 20));       // 0-4 MiB fp32 [8192][128]
  u16* q_bf = (u16*)(ws + (4ull << 20));         // 4-6 (dead after attn)
  u16* k_bf = (u16*)(ws + (6ull << 20));         // 6-8 (dead after attn)
  u16* vt = (u16*)(ws + (8ull << 20));           // 8-10 (dead after attn)
  float* Opart = (float*)(ws + (10ull << 20));   // 10-18 [2][32][2048][16] fp32
  float* out1f = (float*)(ws + (4ull << 20));    // reuse 4-8 after attn
  u16* out1b = (u16*)(ws + (8ull << 20));        // reuse 8-10 after attn
  float* yy = (float*)(ws + (10ull << 20));      // reuse 10-14 after ln1
  float* mf = (float*)(ws + (18ull << 20));      // 18.0-18.03 mask addends [B][2048]
  float* Lpart = (float*)(ws + (18ull << 20) + (1ull << 19));  // 18.5-19 [2][32][2048]

  k_maskf<<<32, 256, 0, stream>>>(mask, mf);
  k_proj<<<dim3(64, 3), 256, 0, stream>>>(q, k, v, Wq, Wk, Wv, bq, bk, bv,
                                          qp, q_bf, k_bf, vt);
  k_attn3<<<dim3(16, 32, 2), 256, 0, stream>>>(q_bf, k_bf, vt, mf, Opart, Lpart);
  k_ln1<<<2048, 256, 0, stream>>>(qp, Opart, Lpart, g1, b1, out1f, out1b);
  k_mlp<<<64, 256, 0, stream>>>(out1b, out1f, Wo, bo, yy);
  k_ln2<<<2048, 256, 0, stream>>>(yy, g2, b2, (float*)d_out);
}

// Round 4
// 73.499 us; speedup vs baseline: 1.6352x; 1.2018x over previous
//
#include <hip/hip_runtime.h>

#define DEV __device__ __forceinline__

typedef unsigned short u16;
typedef unsigned int u32;
typedef float f32x4 __attribute__((ext_vector_type(4)));
typedef float f32x16 __attribute__((ext_vector_type(16)));
typedef __bf16 b16x8 __attribute__((ext_vector_type(8)));
typedef u16 u16x8 __attribute__((ext_vector_type(8)));
typedef u16 u16x4 __attribute__((ext_vector_type(4)));
typedef u32 u32x4 __attribute__((ext_vector_type(4)));

// 1/sqrt(D) * log2(e): QK^T logits directly in log2 units (exp -> v_exp_f32)
#define QSCALE (0.08838834764831845f * 1.44269504089f)

DEV u16 bfr(float x) {  // fp32 -> bf16 RNE
  u32 u = __builtin_bit_cast(u32, x);
  u32 r = u + 0x7fffu + ((u >> 16) & 1u);
  return (u16)(r >> 16);
}

DEV f32x4 mfma16(b16x8 a, b16x8 b, f32x4 c) {
  return __builtin_amdgcn_mfma_f32_16x16x32_bf16(a, b, c, 0, 0, 0);
}

DEV void plswap(u32& a, u32& b) {  // a' = [a.lo32lanes, b.lo32lanes]; b' = [a.hi, b.hi]
  asm volatile("v_permlane32_swap_b32 %0, %1" : "+v"(a), "+v"(b));
}

DEV float fexp2(float x) {  // raw v_exp_f32: 2^x, no libm legalization
  float r;
  asm("v_exp_f32 %0, %1" : "=v"(r) : "v"(x));
  return r;
}

DEV void gll16(const void* g, void* l) {
  __builtin_amdgcn_global_load_lds((const __attribute__((address_space(1))) u32*)g,
                                   (__attribute__((address_space(3))) u32*)l, 16, 0, 0);
}
DEV void gll4(const void* g, void* l) {
  __builtin_amdgcn_global_load_lds((const __attribute__((address_space(1))) u32*)g,
                                   (__attribute__((address_space(3))) u32*)l, 4, 0, 0);
}

// ---------------------------------------------------------------------------
// K0: mask -> f32 addend (0 / -1e30).  grid 32, 256 threads.
// ---------------------------------------------------------------------------
__global__ __launch_bounds__(256) void k_maskf(const int* __restrict__ mask,
                                               float* __restrict__ mf) {
  int i = blockIdx.x * 256 + threadIdx.x;
  mf[i] = mask[i] ? 0.f : -1e30f;
}

// ---------------------------------------------------------------------------
// K1: fused QKV projection.  grid (64, 3), 256 threads.
// mode 0: qp fp32 + q_bf (pre-scaled by QSCALE); mode 1: k_bf; mode 2: vt.
// ---------------------------------------------------------------------------
__global__ __launch_bounds__(256) void k_proj(
    const float* __restrict__ Xq, const float* __restrict__ Xk, const float* __restrict__ Xv,
    const float* __restrict__ Wq, const float* __restrict__ Wk, const float* __restrict__ Wv,
    const float* __restrict__ bq, const float* __restrict__ bk, const float* __restrict__ bv,
    float* __restrict__ qp, u16* __restrict__ q_bf, u16* __restrict__ k_bf,
    u16* __restrict__ vt) {
  __shared__ __align__(16) u16 Xs[128 * 128];
  __shared__ __align__(16) u16 Ws[128 * 128];
  const int tid = threadIdx.x;
  const int mode = blockIdx.y;
  const float* X = (mode == 0) ? Xq : (mode == 1 ? Xk : Xv);
  const float* W = (mode == 0) ? Wq : (mode == 1 ? Wk : Wv);
  const float* bias = (mode == 0) ? bq : (mode == 1 ? bk : bv);
  const int row0 = blockIdx.x * 128;
  char* xb = (char*)Xs;
  char* wb = (char*)Ws;

#pragma unroll
  for (int i = 0; i < 8; ++i) {
    int s = tid + i * 256;
    int row = s >> 4;
    int c0 = (s & 15) * 8;
    const float* src = X + (size_t)(row0 + row) * 128 + c0;
    float4 f0 = *(const float4*)src;
    float4 f1 = *(const float4*)(src + 4);
    u16x8 hv;
    hv[0] = bfr(f0.x); hv[1] = bfr(f0.y); hv[2] = bfr(f0.z); hv[3] = bfr(f0.w);
    hv[4] = bfr(f1.x); hv[5] = bfr(f1.y); hv[6] = bfr(f1.z); hv[7] = bfr(f1.w);
    *(u16x8*)(xb + ((s * 16) ^ ((row & 7) << 4))) = hv;
  }
#pragma unroll
  for (int i = 0; i < 16; ++i) {
    int vecid = i * 256 + tid;
    int kk = vecid >> 5;
    int n0 = (vecid & 31) * 4;
    float4 f = *(const float4*)(W + (size_t)kk * 128 + n0);
    float ff[4] = {f.x, f.y, f.z, f.w};
#pragma unroll
    for (int j = 0; j < 4; ++j) {
      int n = n0 + j;
      *(u16*)(wb + ((n * 256 + kk * 2) ^ ((n & 7) << 4))) = bfr(ff[j]);
    }
  }
  __syncthreads();

  const int lane = tid & 63, wid = tid >> 6;
  const int g = lane >> 4, c = lane & 15;
  const int wi = wid >> 1, wj = wid & 1;

  f32x4 acc[4][4];
#pragma unroll
  for (int a = 0; a < 4; ++a)
#pragma unroll
    for (int b2 = 0; b2 < 4; ++b2) acc[a][b2] = f32x4{0.f, 0.f, 0.f, 0.f};

#pragma unroll
  for (int kk = 0; kk < 4; ++kk) {
    b16x8 af[4], bfv[4];
#pragma unroll
    for (int t = 0; t < 4; ++t) {
      int row = wi * 64 + t * 16 + c;
      af[t] = *(const b16x8*)(xb + ((row * 256 + kk * 64 + g * 16) ^ ((row & 7) << 4)));
      int col = wj * 64 + t * 16 + c;
      bfv[t] = *(const b16x8*)(wb + ((col * 256 + kk * 64 + g * 16) ^ ((col & 7) << 4)));
    }
#pragma unroll
    for (int ti = 0; ti < 4; ++ti)
#pragma unroll
      for (int tj = 0; tj < 4; ++tj) acc[ti][tj] = mfma16(af[ti], bfv[tj], acc[ti][tj]);
  }

#pragma unroll
  for (int tj = 0; tj < 4; ++tj) {
    int col = wj * 64 + tj * 16 + c;
    float bia = bias[col];
    int h = col >> 4, dh = col & 15;
#pragma unroll
    for (int ti = 0; ti < 4; ++ti) {
      int nbase = row0 + wi * 64 + ti * 16 + g * 4;
      f32x4 v4 = acc[ti][tj];
      if (mode == 2) {
        u16x4 pk;
#pragma unroll
        for (int r = 0; r < 4; ++r) pk[r] = bfr(v4[r] + bia);
        int bb2 = nbase >> 11, n = nbase & 2047;
        *(u16x4*)(vt + ((((size_t)bb2 * 8 + h) * 16 + dh) << 11) + n) = pk;
      } else {
        u16* dst = (mode == 0) ? q_bf : k_bf;
        float sc = (mode == 0) ? QSCALE : 1.0f;
#pragma unroll
        for (int r = 0; r < 4; ++r) {
          int rowg = nbase + r;
          float val = v4[r] + bia;
          if (mode == 0) qp[(size_t)rowg * 128 + col] = val;
          int bb2 = rowg >> 11, n = rowg & 2047;
          dst[((((size_t)bb2 * 8 + h) * 2048 + n) << 4) + dh] = bfr(val * sc);
        }
      }
    }
  }
}

// ---------------------------------------------------------------------------
// K2: flash attention, swapped-QK 32x32x16, fixed-max softmax, MFMA row-sum.
// grid (NQ/128, B*H, SPLIT=4), 256 threads (4 waves x 32 q-rows).
// 8 blocks/CU (LDS 17.9KB x 8 = 143KB) -> 32 waves/CU theoretical.
// Writes bf16 un-normalized O partials + bf16 l partials; combine in k_ln1.
// ---------------------------------------------------------------------------
__global__ __launch_bounds__(256) void k_attn4(
    const u16* __restrict__ q_bf, const u16* __restrict__ k_bf,
    const u16* __restrict__ vt, const float* __restrict__ mf,
    u16* __restrict__ OpartB, u16* __restrict__ LpartB) {
  __shared__ __align__(16) u16 Ks[2][128 * 16];    // [key][dh] linear
  __shared__ __align__(16) u16 Vs[2][17 * 128];    // [dh][k] swizzled + ones row at dh=16
  __shared__ __align__(16) float Mf2[2][128];      // mask addends
  const int tid = threadIdx.x, lane = tid & 63, wid = tid >> 6;
  const int q = lane & 31, h = lane >> 5;
  const int bh = blockIdx.y, b = bh >> 3;
  const int z = blockIdx.z;
  const int q0 = blockIdx.x * 128 + wid * 32;

  const u16* Kg = k_bf + (size_t)bh * 2048 * 16;
  const u16* Vg = vt + (size_t)bh * 16 * 2048;
  const float* Mg = mf + (size_t)b * 2048;

  // Q B-fragment (col=q, k=dh): in regs all kernel
  b16x8 qf = *(const b16x8*)(q_bf + (((size_t)bh * 2048 + q0 + q) << 4) + h * 8);

  // ones rows (dh=16) for both buffers: rowsum-by-MFMA column
  if (tid < 32) {
    u16x8 ov;
#pragma unroll
    for (int i = 0; i < 8; ++i) ov[i] = 0x3F80;  // bf16 1.0
    *(u16x8*)(&Vs[tid >> 4][16 * 128 + (tid & 15) * 8]) = ov;
  }

  f32x16 oacc = {};

  auto stage = [&](int bufi, int ct2) {
    const int kt0 = ct2 * 128;
    gll16(Kg + (((size_t)(kt0 + wid * 32)) << 4) + lane * 8, &Ks[bufi][wid * 512]);
    {
      const int dhs = wid * 4 + (lane >> 4);
      const int ts = (lane & 15) ^ (dhs & 7);
      gll16(Vg + (size_t)dhs * 2048 + kt0 + ts * 8, &Vs[bufi][wid * 512]);
    }
    if (wid < 2) gll4(Mg + kt0 + wid * 64 + lane, &Mf2[bufi][wid * 64]);
  };

  const int ct0 = z * 4;
  stage(0, ct0);
  const int dhc = (q < 16) ? q : 16;  // V col: dh, clamped to ones row

  for (int ct = ct0; ct < ct0 + 4; ++ct) {
    const int cur = ct & 1;
    __syncthreads();
    if (ct < ct0 + 3) stage(cur ^ 1, ct + 1);
    const u16* ksb = Ks[cur];
    const char* vsb = (const char*)Vs[cur];
    const float* mfb = Mf2[cur];

#pragma unroll
    for (int kt = 0; kt < 4; ++kt) {
      // S^T = mfma(A=K[32k x 16dh], B=Q[32q x 16dh]); lane: col=q, rows=keys
      b16x8 kf = *(const b16x8*)(ksb + (kt * 32 + q) * 16 + h * 8);
      f32x16 zz = {};
      f32x16 st = __builtin_amdgcn_mfma_f32_32x32x16_bf16(kf, qf, zz, 0, 0, 0);

      // mask addends for keys (r&3)+8*(r>>2)+4h
      const float* mrow = mfb + kt * 32 + 4 * h;
      f32x4 ma[4];
      ma[0] = *(const f32x4*)(mrow);
      ma[1] = *(const f32x4*)(mrow + 8);
      ma[2] = *(const f32x4*)(mrow + 16);
      ma[3] = *(const f32x4*)(mrow + 24);

      // fixed-max softmax: p = 2^(s + mask); masked -> v_exp(-1e30) = 0
      float p[16];
#pragma unroll
      for (int g2 = 0; g2 < 4; ++g2)
#pragma unroll
        for (int j = 0; j < 4; ++j) p[g2 * 4 + j] = fexp2(st[g2 * 4 + j] + ma[g2][j]);

      // T12: P -> bf16 PV A-fragments in-register
      u32 w[8];
#pragma unroll
      for (int i = 0; i < 8; ++i)
        asm("v_cvt_pk_bf16_f32 %0, %1, %2" : "=v"(w[i]) : "v"(p[2 * i]), "v"(p[2 * i + 1]));
      plswap(w[0], w[2]); plswap(w[1], w[3]);
      plswap(w[4], w[6]); plswap(w[5], w[7]);
      u32x4 f0v = {w[0], w[1], w[2], w[3]};
      u32x4 f1v = {w[4], w[5], w[6], w[7]};
      b16x8 F0 = __builtin_bit_cast(b16x8, f0v);
      b16x8 F1 = __builtin_bit_cast(b16x8, f1v);

      // V B-fragments (col=dh or ones row), swizzled slots
      const int t0 = (kt * 4 + h) ^ (dhc & 7);
      const int t1 = (kt * 4 + 2 + h) ^ (dhc & 7);
      b16x8 vf0 = *(const b16x8*)(vsb + (dhc * 16 + t0) * 16);
      b16x8 vf1 = *(const b16x8*)(vsb + (dhc * 16 + t1) * 16);
      oacc = __builtin_amdgcn_mfma_f32_32x32x16_bf16(F0, vf0, oacc, 0, 0, 0);
      oacc = __builtin_amdgcn_mfma_f32_32x32x16_bf16(F1, vf1, oacc, 0, 0, 0);
    }
  }

  // epilogue: cols 0-15 = un-normalized O (bf16); col 16 = l (bf16)
  const size_t rowbase = (size_t)(z * 32 + bh) * 2048 + q0;
  if (q < 16) {
    u16* op = OpartB + rowbase * 16 + q;
#pragma unroll
    for (int g2 = 0; g2 < 4; ++g2)
#pragma unroll
      for (int j = 0; j < 4; ++j) {
        int row = j + 8 * g2 + 4 * h;
        op[(size_t)row * 16] = bfr(oacc[g2 * 4 + j]);
      }
  } else if (q == 16) {
    u16* lp = LpartB + rowbase;
#pragma unroll
    for (int r = 0; r < 16; ++r) {
      int row = (r & 3) + 8 * (r >> 2) + 4 * h;
      lp[row] = bfr(oacc[r]);
    }
  }
}

// ---------------------------------------------------------------------------
// K3: combine 4 O/l partials + LN1 over x = qp + o.  grid 2048, 256 threads.
// ---------------------------------------------------------------------------
__global__ __launch_bounds__(256) void k_ln1(
    const float* __restrict__ qp, const u16* __restrict__ OpartB,
    const u16* __restrict__ LpartB,
    const float* __restrict__ g1, const float* __restrict__ b1,
    float* __restrict__ out1f, u16* __restrict__ out1b) {
  const int lane = threadIdx.x & 63;
  const int row = blockIdx.x * 4 + (threadIdx.x >> 6);
  const int b = row >> 11, q = row & 2047;
  const int head = lane >> 3;        // col pair c0 = lane*2; head = c0>>4
  const int dh = (lane & 7) * 2;
  const size_t pb = (size_t)(b * 8 + head) * 2048 + q;
  const size_t SPLIT_O = (size_t)32 * 2048 * 16;
  const size_t SPLIT_L = (size_t)32 * 2048;
  float ox = 0.f, oy = 0.f, l = 0.f;
#pragma unroll
  for (int z = 0; z < 4; ++z) {
    u32 w = *(const u32*)(OpartB + z * SPLIT_O + pb * 16 + dh);
    ox += __builtin_bit_cast(float, w << 16);
    oy += __builtin_bit_cast(float, w & 0xffff0000u);
    l += __builtin_bit_cast(float, (u32)LpartB[z * SPLIT_L + pb] << 16);
  }
  float inv = (l > 0.f) ? 1.0f / l : 0.f;
  ox *= inv; oy *= inv;

  const size_t base = (size_t)row * 128 + lane * 2;
  float2 a = *(const float2*)(qp + base);
  float x0 = a.x + ox, x1 = a.y + oy;
  float sum = x0 + x1, sq = x0 * x0 + x1 * x1;
#pragma unroll
  for (int off = 1; off < 64; off <<= 1) {
    sum += __shfl_xor(sum, off);
    sq += __shfl_xor(sq, off);
  }
  float mu = sum * (1.f / 128.f);
  float rstd = rsqrtf(sq * (1.f / 128.f) - mu * mu + 1e-6f);
  float2 gg = *(const float2*)(g1 + lane * 2);
  float2 be = *(const float2*)(b1 + lane * 2);
  float y0 = (x0 - mu) * rstd * gg.x + be.x;
  float y1 = (x1 - mu) * rstd * gg.y + be.y;
  *(float2*)(out1f + base) = make_float2(y0, y1);
  *(u32*)(out1b + base) = (u32)bfr(y0) | ((u32)bfr(y1) << 16);
}

// ---------------------------------------------------------------------------
// K4: y = out1 + relu(out1 @ Wo + bo).  grid 64, 256 threads.
// ---------------------------------------------------------------------------
__global__ __launch_bounds__(256) void k_mlp(
    const u16* __restrict__ out1b, const float* __restrict__ out1f,
    const float* __restrict__ Wo, const float* __restrict__ bo, float* __restrict__ y) {
  __shared__ __align__(16) u16 Xs[128 * 128];
  __shared__ __align__(16) u16 Ws[128 * 128];
  const int tid = threadIdx.x;
  const int row0 = blockIdx.x * 128;
  char* xb = (char*)Xs;
  char* wb = (char*)Ws;
#pragma unroll
  for (int i = 0; i < 8; ++i) {
    int s = tid + i * 256;
    int row = s >> 4;
    u16x8 hv = *(const u16x8*)(out1b + (size_t)(row0 + row) * 128 + (s & 15) * 8);
    *(u16x8*)(xb + ((s * 16) ^ ((row & 7) << 4))) = hv;
  }
#pragma unroll
  for (int i = 0; i < 16; ++i) {
    int vecid = i * 256 + tid;
    int kk = vecid >> 5;
    int n0 = (vecid & 31) * 4;
    float4 f = *(const float4*)(Wo + (size_t)kk * 128 + n0);
    float ff[4] = {f.x, f.y, f.z, f.w};
#pragma unroll
    for (int j = 0; j < 4; ++j) {
      int n = n0 + j;
      *(u16*)(wb + ((n * 256 + kk * 2) ^ ((n & 7) << 4))) = bfr(ff[j]);
    }
  }
  __syncthreads();

  const int lane = tid & 63, wid = tid >> 6;
  const int g = lane >> 4, c = lane & 15;
  const int wi = wid >> 1, wj = wid & 1;

  f32x4 acc[4][4];
#pragma unroll
  for (int a = 0; a < 4; ++a)
#pragma unroll
    for (int b2 = 0; b2 < 4; ++b2) acc[a][b2] = f32x4{0.f, 0.f, 0.f, 0.f};

#pragma unroll
  for (int kk = 0; kk < 4; ++kk) {
    b16x8 af[4], bfv[4];
#pragma unroll
    for (int t = 0; t < 4; ++t) {
      int row = wi * 64 + t * 16 + c;
      af[t] = *(const b16x8*)(xb + ((row * 256 + kk * 64 + g * 16) ^ ((row & 7) << 4)));
      int col = wj * 64 + t * 16 + c;
      bfv[t] = *(const b16x8*)(wb + ((col * 256 + kk * 64 + g * 16) ^ ((col & 7) << 4)));
    }
#pragma unroll
    for (int ti = 0; ti < 4; ++ti)
#pragma unroll
      for (int tj = 0; tj < 4; ++tj) acc[ti][tj] = mfma16(af[ti], bfv[tj], acc[ti][tj]);
  }

#pragma unroll
  for (int tj = 0; tj < 4; ++tj) {
    int col = wj * 64 + tj * 16 + c;
    float bia = bo[col];
#pragma unroll
    for (int ti = 0; ti < 4; ++ti) {
#pragma unroll
      for (int r = 0; r < 4; ++r) {
        int rowg = row0 + wi * 64 + ti * 16 + g * 4 + r;
        float val = acc[ti][tj][r] + bia;
        val = fmaxf(val, 0.f) + out1f[(size_t)rowg * 128 + col];
        y[(size_t)rowg * 128 + col] = val;
      }
    }
  }
}

// ---------------------------------------------------------------------------
// K5: final LN2 -> d_out.  grid 2048, 256 threads.
// ---------------------------------------------------------------------------
__global__ __launch_bounds__(256) void k_ln2(
    const float* __restrict__ yv, const float* __restrict__ g2, const float* __restrict__ b2,
    float* __restrict__ out) {
  const int lane = threadIdx.x & 63;
  const int row = blockIdx.x * 4 + (threadIdx.x >> 6);
  const size_t base = (size_t)row * 128 + lane * 2;
  float2 a = *(const float2*)(yv + base);
  float x0 = a.x, x1 = a.y;
  float sum = x0 + x1, sq = x0 * x0 + x1 * x1;
#pragma unroll
  for (int off = 1; off < 64; off <<= 1) {
    sum += __shfl_xor(sum, off);
    sq += __shfl_xor(sq, off);
  }
  float mu = sum * (1.f / 128.f);
  float rstd = rsqrtf(sq * (1.f / 128.f) - mu * mu + 1e-6f);
  float2 gg = *(const float2*)(g2 + lane * 2);
  float2 be = *(const float2*)(b2 + lane * 2);
  *(float2*)(out + base) =
      make_float2((x0 - mu) * rstd * gg.x + be.x, (x1 - mu) * rstd * gg.y + be.y);
}

// ---------------------------------------------------------------------------
extern "C" void kernel_launch(void* const* d_in, const int* in_sizes, int n_in,
                              void* d_out, int out_size, void* d_ws, size_t ws_size,
                              hipStream_t stream) {
  const float* q = (const float*)d_in[0];
  const float* k = (const float*)d_in[1];
  const float* v = (const float*)d_in[2];
  const int* mask = (const int*)d_in[3];
  const float* Wq = (const float*)d_in[4];
  const float* bq = (const float*)d_in[5];
  const float* Wk = (const float*)d_in[6];
  const float* bk = (const float*)d_in[7];
  const float* Wv = (const float*)d_in[8];
  const float* bv = (const float*)d_in[9];
  const float* Wo = (const float*)d_in[10];
  const float* bo = (const float*)d_in[11];
  const float* g1 = (const float*)d_in[12];
  const float* b1 = (const float*)d_in[13];
  const float* g2 = (const float*)d_in[14];
  const float* b2 = (const float*)d_in[15];

  // ws layout (18.6 MiB high-water, lifetime-overlapped):
  char* ws = (char*)d_ws;
  float* qp = (float*)(ws + (0ull << 20));       // 0-4 MiB fp32 [8192][128]
  u16* q_bf = (u16*)(ws + (4ull << 20));         // 4-6 (dead after attn)
  u16* k_bf = (u16*)(ws + (6ull << 20));         // 6-8 (dead after attn)
  u16* vt = (u16*)(ws + (8ull << 20));           // 8-10 (dead after attn)
  u16* OpartB = (u16*)(ws + (10ull << 20));      // 10-18 [4][32][2048][16] bf16
  u16* LpartB = (u16*)(ws + (18ull << 20));      // 18-18.5 [4][32][2048] bf16
  float* mf = (float*)(ws + (18ull << 20) + (1ull << 19));  // 18.5-18.53 [B][2048]
  float* out1f = (float*)(ws + (4ull << 20));    // reuse 4-8 after attn
  u16* out1b = (u16*)(ws + (8ull << 20));        // reuse 8-10 after attn
  float* yy = (float*)(ws + (10ull << 20));      // reuse 10-14 after ln1

  k_maskf<<<32, 256, 0, stream>>>(mask, mf);
  k_proj<<<dim3(64, 3), 256, 0, stream>>>(q, k, v, Wq, Wk, Wv, bq, bk, bv,
                                          qp, q_bf, k_bf, vt);
  k_attn4<<<dim3(16, 32, 4), 256, 0, stream>>>(q_bf, k_bf, vt, mf, OpartB, LpartB);
  k_ln1<<<2048, 256, 0, stream>>>(qp, OpartB, LpartB, g1, b1, out1f, out1b);
  k_mlp<<<64, 256, 0, stream>>>(out1b, out1f, Wo, bo, yy);
  k_ln2<<<2048, 256, 0, stream>>>(yy, g2, b2, (float*)d_out);
}

// Round 5
// 54.967 us; speedup vs baseline: 2.1865x; 1.3372x over previous
//
#include <hip/hip_runtime.h>

#define DEV __device__ __forceinline__

typedef unsigned short u16;
typedef unsigned int u32;
typedef float f32x4 __attribute__((ext_vector_type(4)));
typedef float f32x16 __attribute__((ext_vector_type(16)));
typedef __bf16 b16x8 __attribute__((ext_vector_type(8)));
typedef u16 u16x8 __attribute__((ext_vector_type(8)));
typedef u16 u16x4 __attribute__((ext_vector_type(4)));
typedef u32 u32x4 __attribute__((ext_vector_type(4)));

// 1/sqrt(D) * log2(e): QK^T logits directly in log2 units (exp -> v_exp_f32)
#define QSCALE (0.08838834764831845f * 1.44269504089f)

DEV u16 bfr(float x) {  // fp32 -> bf16 RNE
  u32 u = __builtin_bit_cast(u32, x);
  u32 r = u + 0x7fffu + ((u >> 16) & 1u);
  return (u16)(r >> 16);
}

DEV f32x4 mfma16(b16x8 a, b16x8 b, f32x4 c) {
  return __builtin_amdgcn_mfma_f32_16x16x32_bf16(a, b, c, 0, 0, 0);
}

DEV void plswap(u32& a, u32& b) {  // a' = [a.lo32lanes, b.lo32lanes]; b' = [a.hi, b.hi]
  asm volatile("v_permlane32_swap_b32 %0, %1" : "+v"(a), "+v"(b));
}

DEV float fexp2(float x) {  // raw v_exp_f32: 2^x, no libm legalization
  float r;
  asm("v_exp_f32 %0, %1" : "=v"(r) : "v"(x));
  return r;
}

DEV void gll16(const void* g, void* l) {
  __builtin_amdgcn_global_load_lds((const __attribute__((address_space(1))) u32*)g,
                                   (__attribute__((address_space(3))) u32*)l, 16, 0, 0);
}
DEV void gll4(const void* g, void* l) {
  __builtin_amdgcn_global_load_lds((const __attribute__((address_space(1))) u32*)g,
                                   (__attribute__((address_space(3))) u32*)l, 4, 0, 0);
}

// ---------------------------------------------------------------------------
// K1: fused QKV projection + mask->f32 conversion.  grid (64, 3), 256 threads.
// mode 0: qp fp32 + q_bf (pre-scaled by QSCALE) [+ mask conv on blocks <32];
// mode 1: k_bf; mode 2: vt (transposed).
// ---------------------------------------------------------------------------
__global__ __launch_bounds__(256) void k_proj(
    const float* __restrict__ Xq, const float* __restrict__ Xk, const float* __restrict__ Xv,
    const float* __restrict__ Wq, const float* __restrict__ Wk, const float* __restrict__ Wv,
    const float* __restrict__ bq, const float* __restrict__ bk, const float* __restrict__ bv,
    const int* __restrict__ mask, float* __restrict__ mf,
    float* __restrict__ qp, u16* __restrict__ q_bf, u16* __restrict__ k_bf,
    u16* __restrict__ vt) {
  __shared__ __align__(16) u16 Xs[128 * 128];
  __shared__ __align__(16) u16 Ws[128 * 128];
  const int tid = threadIdx.x;
  const int mode = blockIdx.y;
  const float* X = (mode == 0) ? Xq : (mode == 1 ? Xk : Xv);
  const float* W = (mode == 0) ? Wq : (mode == 1 ? Wk : Wv);
  const float* bias = (mode == 0) ? bq : (mode == 1 ? bk : bv);
  const int row0 = blockIdx.x * 128;
  char* xb = (char*)Xs;
  char* wb = (char*)Ws;

  if (mode == 0 && blockIdx.x < 32) {  // folded k_maskf
    int i = blockIdx.x * 256 + tid;
    mf[i] = mask[i] ? 0.f : -1e30f;
  }

#pragma unroll
  for (int i = 0; i < 8; ++i) {
    int s = tid + i * 256;
    int row = s >> 4;
    int c0 = (s & 15) * 8;
    const float* src = X + (size_t)(row0 + row) * 128 + c0;
    float4 f0 = *(const float4*)src;
    float4 f1 = *(const float4*)(src + 4);
    u16x8 hv;
    hv[0] = bfr(f0.x); hv[1] = bfr(f0.y); hv[2] = bfr(f0.z); hv[3] = bfr(f0.w);
    hv[4] = bfr(f1.x); hv[5] = bfr(f1.y); hv[6] = bfr(f1.z); hv[7] = bfr(f1.w);
    *(u16x8*)(xb + ((s * 16) ^ ((row & 7) << 4))) = hv;
  }
#pragma unroll
  for (int i = 0; i < 16; ++i) {
    int vecid = i * 256 + tid;
    int kk = vecid >> 5;
    int n0 = (vecid & 31) * 4;
    float4 f = *(const float4*)(W + (size_t)kk * 128 + n0);
    float ff[4] = {f.x, f.y, f.z, f.w};
#pragma unroll
    for (int j = 0; j < 4; ++j) {
      int n = n0 + j;
      *(u16*)(wb + ((n * 256 + kk * 2) ^ ((n & 7) << 4))) = bfr(ff[j]);
    }
  }
  __syncthreads();

  const int lane = tid & 63, wid = tid >> 6;
  const int g = lane >> 4, c = lane & 15;
  const int wi = wid >> 1, wj = wid & 1;

  f32x4 acc[4][4];
#pragma unroll
  for (int a = 0; a < 4; ++a)
#pragma unroll
    for (int b2 = 0; b2 < 4; ++b2) acc[a][b2] = f32x4{0.f, 0.f, 0.f, 0.f};

#pragma unroll
  for (int kk = 0; kk < 4; ++kk) {
    b16x8 af[4], bfv[4];
#pragma unroll
    for (int t = 0; t < 4; ++t) {
      int row = wi * 64 + t * 16 + c;
      af[t] = *(const b16x8*)(xb + ((row * 256 + kk * 64 + g * 16) ^ ((row & 7) << 4)));
      int col = wj * 64 + t * 16 + c;
      bfv[t] = *(const b16x8*)(wb + ((col * 256 + kk * 64 + g * 16) ^ ((col & 7) << 4)));
    }
#pragma unroll
    for (int ti = 0; ti < 4; ++ti)
#pragma unroll
      for (int tj = 0; tj < 4; ++tj) acc[ti][tj] = mfma16(af[ti], bfv[tj], acc[ti][tj]);
  }

#pragma unroll
  for (int tj = 0; tj < 4; ++tj) {
    int col = wj * 64 + tj * 16 + c;
    float bia = bias[col];
    int h = col >> 4, dh = col & 15;
#pragma unroll
    for (int ti = 0; ti < 4; ++ti) {
      int nbase = row0 + wi * 64 + ti * 16 + g * 4;
      f32x4 v4 = acc[ti][tj];
      if (mode == 2) {
        u16x4 pk;
#pragma unroll
        for (int r = 0; r < 4; ++r) pk[r] = bfr(v4[r] + bia);
        int bb2 = nbase >> 11, n = nbase & 2047;
        *(u16x4*)(vt + ((((size_t)bb2 * 8 + h) * 16 + dh) << 11) + n) = pk;
      } else {
        u16* dst = (mode == 0) ? q_bf : k_bf;
        float sc = (mode == 0) ? QSCALE : 1.0f;
#pragma unroll
        for (int r = 0; r < 4; ++r) {
          int rowg = nbase + r;
          float val = v4[r] + bia;
          if (mode == 0) qp[(size_t)rowg * 128 + col] = val;
          int bb2 = rowg >> 11, n = rowg & 2047;
          dst[((((size_t)bb2 * 8 + h) * 2048 + n) << 4) + dh] = bfr(val * sc);
        }
      }
    }
  }
}

// ---------------------------------------------------------------------------
// K2: flash attention, swapped-QK 32x32x16, mask-as-MFMA-C, MFMA row-sum.
// grid (NQ/128, B*H, SPLIT=4), 256 threads (4 waves x 32 q-rows).
// K tile slot-swizzled sigma(s)=s^((s>>3)&7) via pre-swizzled global source.
// ---------------------------------------------------------------------------
__global__ __launch_bounds__(256) void k_attn5(
    const u16* __restrict__ q_bf, const u16* __restrict__ k_bf,
    const u16* __restrict__ vt, const float* __restrict__ mf,
    u16* __restrict__ OpartB, u16* __restrict__ LpartB) {
  __shared__ __align__(16) u16 Ks[2][128 * 16];    // [slot sigma] (16B slots)
  __shared__ __align__(16) u16 Vs[2][17 * 128];    // [dh][k] swizzled + ones row at dh=16
  __shared__ __align__(16) float Mf2[2][128];      // mask addends
  const int tid = threadIdx.x, lane = tid & 63, wid = tid >> 6;
  const int q = lane & 31, h = lane >> 5;
  const int bh = blockIdx.y, b = bh >> 3;
  const int z = blockIdx.z;
  const int q0 = blockIdx.x * 128 + wid * 32;

  const u16* Kg = k_bf + (size_t)bh * 2048 * 16;
  const u16* Vg = vt + (size_t)bh * 16 * 2048;
  const float* Mg = mf + (size_t)b * 2048;

  // Q B-fragment (col=q, k=dh): in regs all kernel
  b16x8 qf = *(const b16x8*)(q_bf + (((size_t)bh * 2048 + q0 + q) << 4) + h * 8);

  // ones rows (dh=16) for both buffers: rowsum-by-MFMA column
  if (tid < 32) {
    u16x8 ov;
#pragma unroll
    for (int i = 0; i < 8; ++i) ov[i] = 0x3F80;  // bf16 1.0
    *(u16x8*)(&Vs[tid >> 4][16 * 128 + (tid & 15) * 8]) = ov;
  }

  f32x16 oacc = {};

  auto stage = [&](int bufi, int ct2) {
    const int kt0 = ct2 * 128;
    // K: dest slot t linear; source slot sigma(t) (involution) -> swizzled LDS
    {
      const int t = wid * 64 + lane;
      const int ssrc = t ^ ((t >> 3) & 7);
      gll16(Kg + (size_t)kt0 * 16 + ssrc * 8, &Ks[bufi][wid * 512]);
    }
    {
      const int dhs = wid * 4 + (lane >> 4);
      const int ts = (lane & 15) ^ (dhs & 7);
      gll16(Vg + (size_t)dhs * 2048 + kt0 + ts * 8, &Vs[bufi][wid * 512]);
    }
    if (wid < 2) gll4(Mg + kt0 + wid * 64 + lane, &Mf2[bufi][wid * 64]);
  };

  const int ct0 = z * 4;
  stage(0, ct0);
  const int dhc = (q < 16) ? q : 16;  // V col: dh, clamped to ones row

  for (int ct = ct0; ct < ct0 + 4; ++ct) {
    const int cur = ct & 1;
    __syncthreads();
    if (ct < ct0 + 3) stage(cur ^ 1, ct + 1);
    const char* ksb = (const char*)Ks[cur];
    const char* vsb = (const char*)Vs[cur];
    const float* mfb = Mf2[cur];

#pragma unroll
    for (int kt = 0; kt < 4; ++kt) {
      // K A-fragment from sigma-swizzled slots
      const int s = kt * 64 + q * 2 + h;
      const int srd = s ^ ((s >> 3) & 7);
      b16x8 kf = *(const b16x8*)(ksb + srd * 16);

      // mask addends as MFMA C-input: C[r] = mf[key=(r&3)+8*(r>>2)+4h]
      const float* mrow = mfb + kt * 32 + 4 * h;
      f32x4 ma0 = *(const f32x4*)(mrow);
      f32x4 ma1 = *(const f32x4*)(mrow + 8);
      f32x4 ma2 = *(const f32x4*)(mrow + 16);
      f32x4 ma3 = *(const f32x4*)(mrow + 24);
      f32x16 cc;
#pragma unroll
      for (int j = 0; j < 4; ++j) {
        cc[j] = ma0[j]; cc[4 + j] = ma1[j]; cc[8 + j] = ma2[j]; cc[12 + j] = ma3[j];
      }
      // S^T + mask = mfma(A=K, B=Q, C=mask); lane: col=q, rows=keys
      f32x16 st = __builtin_amdgcn_mfma_f32_32x32x16_bf16(kf, qf, cc, 0, 0, 0);

      // fixed-max softmax: p = 2^(st); masked -> v_exp(-1e30) = 0
      float p[16];
#pragma unroll
      for (int r = 0; r < 16; ++r) p[r] = fexp2(st[r]);

      // T12: P -> bf16 PV A-fragments in-register
      u32 w[8];
#pragma unroll
      for (int i = 0; i < 8; ++i)
        asm("v_cvt_pk_bf16_f32 %0, %1, %2" : "=v"(w[i]) : "v"(p[2 * i]), "v"(p[2 * i + 1]));
      plswap(w[0], w[2]); plswap(w[1], w[3]);
      plswap(w[4], w[6]); plswap(w[5], w[7]);
      u32x4 f0v = {w[0], w[1], w[2], w[3]};
      u32x4 f1v = {w[4], w[5], w[6], w[7]};
      b16x8 F0 = __builtin_bit_cast(b16x8, f0v);
      b16x8 F1 = __builtin_bit_cast(b16x8, f1v);

      // V B-fragments (col=dh or ones row), swizzled slots
      const int t0 = (kt * 4 + h) ^ (dhc & 7);
      const int t1 = (kt * 4 + 2 + h) ^ (dhc & 7);
      b16x8 vf0 = *(const b16x8*)(vsb + (dhc * 16 + t0) * 16);
      b16x8 vf1 = *(const b16x8*)(vsb + (dhc * 16 + t1) * 16);
      oacc = __builtin_amdgcn_mfma_f32_32x32x16_bf16(F0, vf0, oacc, 0, 0, 0);
      oacc = __builtin_amdgcn_mfma_f32_32x32x16_bf16(F1, vf1, oacc, 0, 0, 0);
    }
  }

  // epilogue: cols 0-15 = un-normalized O (bf16); col 16 = l (bf16)
  const size_t rowbase = (size_t)(z * 32 + bh) * 2048 + q0;
  if (q < 16) {
    u16* op = OpartB + rowbase * 16 + q;
#pragma unroll
    for (int g2 = 0; g2 < 4; ++g2)
#pragma unroll
      for (int j = 0; j < 4; ++j) {
        int row = j + 8 * g2 + 4 * h;
        op[(size_t)row * 16] = bfr(oacc[g2 * 4 + j]);
      }
  } else if (q == 16) {
    u16* lp = LpartB + rowbase;
#pragma unroll
    for (int r = 0; r < 16; ++r) {
      int row = (r & 3) + 8 * (r >> 2) + 4 * h;
      lp[row] = bfr(oacc[r]);
    }
  }
}

// ---------------------------------------------------------------------------
// K3: fused tail: combine partials + LN1 -> MLP GEMM -> relu+residual -> LN2.
// grid 256 blocks x 32 rows, 256 threads (4 waves).  LDS 72KB -> 2 blk/CU.
// ---------------------------------------------------------------------------
__global__ __launch_bounds__(256) void k_tail(
    const float* __restrict__ qp, const u16* __restrict__ OpartB,
    const u16* __restrict__ LpartB,
    const float* __restrict__ g1, const float* __restrict__ b1,
    const float* __restrict__ Wo, const float* __restrict__ bo,
    const float* __restrict__ g2, const float* __restrict__ b2,
    float* __restrict__ out) {
  __shared__ __align__(16) u16 Ws[128 * 128];   // Wo^T bf16 swizzled (32KB)
  __shared__ __align__(16) u16 Xs[32 * 128];    // out1 bf16 swizzled (8KB)
  __shared__ __align__(16) float Xf[32 * 128];  // out1 f32, row-XOR (16KB)
  __shared__ __align__(16) float Yf[32 * 128];  // y f32, row-XOR (16KB)
  const int tid = threadIdx.x, lane = tid & 63, wid = tid >> 6;
  char* wb = (char*)Ws;
  char* xb = (char*)Xs;
  char* xfb = (char*)Xf;
  char* yfb = (char*)Yf;
  const int rows0 = blockIdx.x * 32;
  const int b = rows0 >> 11, n0 = rows0 & 2047;

  // --- stage Wo^T bf16 swizzled (same as proven k_mlp pattern) ---
#pragma unroll
  for (int i = 0; i < 16; ++i) {
    int vecid = i * 256 + tid;
    int kk = vecid >> 5;
    int nn = (vecid & 31) * 4;
    float4 f = *(const float4*)(Wo + (size_t)kk * 128 + nn);
    float ff[4] = {f.x, f.y, f.z, f.w};
#pragma unroll
    for (int j = 0; j < 4; ++j) {
      int n = nn + j;
      *(u16*)(wb + ((n * 256 + kk * 2) ^ ((n & 7) << 4))) = bfr(ff[j]);
    }
  }

  // --- phase A: combine partials + LN1; wave wid owns rows wid*8..+7 ---
  const int head = lane >> 3, dh = (lane & 7) * 2;
  const size_t SPLIT_O = (size_t)32 * 2048 * 16;
  const size_t SPLIT_L = (size_t)32 * 2048;
  float2 gg1 = *(const float2*)(g1 + lane * 2);
  float2 be1 = *(const float2*)(b1 + lane * 2);
#pragma unroll
  for (int rr = 0; rr < 8; ++rr) {
    const int lr = wid * 8 + rr;
    const int rg = rows0 + lr;
    const size_t pb = (size_t)(b * 8 + head) * 2048 + (n0 + lr);
    float ox = 0.f, oy = 0.f, l = 0.f;
#pragma unroll
    for (int zz = 0; zz < 4; ++zz) {
      u32 w = *(const u32*)(OpartB + zz * SPLIT_O + pb * 16 + dh);
      ox += __builtin_bit_cast(float, w << 16);
      oy += __builtin_bit_cast(float, w & 0xffff0000u);
      l += __builtin_bit_cast(float, (u32)LpartB[zz * SPLIT_L + pb] << 16);
    }
    float inv = (l > 0.f) ? 1.0f / l : 0.f;
    float2 a = *(const float2*)(qp + (size_t)rg * 128 + lane * 2);
    float x0 = a.x + ox * inv, x1 = a.y + oy * inv;
    float sum = x0 + x1, sq = x0 * x0 + x1 * x1;
#pragma unroll
    for (int off = 1; off < 64; off <<= 1) {
      sum += __shfl_xor(sum, off);
      sq += __shfl_xor(sq, off);
    }
    float mu = sum * (1.f / 128.f);
    float rstd = rsqrtf(sq * (1.f / 128.f) - mu * mu + 1e-6f);
    float y0 = (x0 - mu) * rstd * gg1.x + be1.x;
    float y1 = (x1 - mu) * rstd * gg1.y + be1.y;
    *(float2*)(xfb + (((lr * 512 + lane * 8)) ^ ((lr & 7) << 4))) = make_float2(y0, y1);
    *(u32*)(xb + ((lr * 256 + lane * 4) ^ ((lr & 7) << 4))) =
        (u32)bfr(y0) | ((u32)bfr(y1) << 16);
  }
  __syncthreads();

  // --- phase B: GEMM out1 @ Wo + relu + residual -> Yf ---
  const int g = lane >> 4, c = lane & 15;
  const int wi = wid >> 1, wj = wid & 1;
  f32x4 acc[4];
#pragma unroll
  for (int t = 0; t < 4; ++t) acc[t] = f32x4{0.f, 0.f, 0.f, 0.f};
#pragma unroll
  for (int kk = 0; kk < 4; ++kk) {
    const int row = wi * 16 + c;
    b16x8 af = *(const b16x8*)(xb + ((row * 256 + kk * 64 + g * 16) ^ ((row & 7) << 4)));
#pragma unroll
    for (int t = 0; t < 4; ++t) {
      int col = wj * 64 + t * 16 + c;
      b16x8 bfv = *(const b16x8*)(wb + ((col * 256 + kk * 64 + g * 16) ^ ((col & 7) << 4)));
      acc[t] = mfma16(af, bfv, acc[t]);
    }
  }
#pragma unroll
  for (int t = 0; t < 4; ++t) {
    const int col = wj * 64 + t * 16 + c;
    const float bia = bo[col];
#pragma unroll
    for (int r = 0; r < 4; ++r) {
      const int lr = wi * 16 + g * 4 + r;
      float o1 = *(const float*)(xfb + ((lr * 512 + col * 4) ^ ((lr & 7) << 4)));
      float val = fmaxf(acc[t][r] + bia, 0.f) + o1;
      *(float*)(yfb + ((lr * 512 + col * 4) ^ ((lr & 7) << 4))) = val;
    }
  }
  __syncthreads();

  // --- phase C: LN2 -> out ---
  float2 gg2 = *(const float2*)(g2 + lane * 2);
  float2 be2 = *(const float2*)(b2 + lane * 2);
#pragma unroll
  for (int rr = 0; rr < 8; ++rr) {
    const int lr = wid * 8 + rr;
    float2 a = *(const float2*)(yfb + ((lr * 512 + lane * 8) ^ ((lr & 7) << 4)));
    float x0 = a.x, x1 = a.y;
    float sum = x0 + x1, sq = x0 * x0 + x1 * x1;
#pragma unroll
    for (int off = 1; off < 64; off <<= 1) {
      sum += __shfl_xor(sum, off);
      sq += __shfl_xor(sq, off);
    }
    float mu = sum * (1.f / 128.f);
    float rstd = rsqrtf(sq * (1.f / 128.f) - mu * mu + 1e-6f);
    *(float2*)(out + (size_t)(rows0 + lr) * 128 + lane * 2) =
        make_float2((x0 - mu) * rstd * gg2.x + be2.x, (x1 - mu) * rstd * gg2.y + be2.y);
  }
}

// ---------------------------------------------------------------------------
extern "C" void kernel_launch(void* const* d_in, const int* in_sizes, int n_in,
                              void* d_out, int out_size, void* d_ws, size_t ws_size,
                              hipStream_t stream) {
  const float* q = (const float*)d_in[0];
  const float* k = (const float*)d_in[1];
  const float* v = (const float*)d_in[2];
  const int* mask = (const int*)d_in[3];
  const float* Wq = (const float*)d_in[4];
  const float* bq = (const float*)d_in[5];
  const float* Wk = (const float*)d_in[6];
  const float* bk = (const float*)d_in[7];
  const float* Wv = (const float*)d_in[8];
  const float* bv = (const float*)d_in[9];
  const float* Wo = (const float*)d_in[10];
  const float* bo = (const float*)d_in[11];
  const float* g1 = (const float*)d_in[12];
  const float* b1 = (const float*)d_in[13];
  const float* g2 = (const float*)d_in[14];
  const float* b2 = (const float*)d_in[15];

  // ws layout (18.6 MiB high-water):
  char* ws = (char*)d_ws;
  float* qp = (float*)(ws + (0ull << 20));       // 0-4 MiB fp32 [8192][128]
  u16* q_bf = (u16*)(ws + (4ull << 20));         // 4-6 MiB
  u16* k_bf = (u16*)(ws + (6ull << 20));         // 6-8 MiB
  u16* vt = (u16*)(ws + (8ull << 20));           // 8-10 MiB
  u16* OpartB = (u16*)(ws + (10ull << 20));      // 10-18 [4][32][2048][16] bf16
  u16* LpartB = (u16*)(ws + (18ull << 20));      // 18-18.5 [4][32][2048] bf16
  float* mf = (float*)(ws + (18ull << 20) + (1ull << 19));  // 18.5-18.53 [B][2048]

  k_proj<<<dim3(64, 3), 256, 0, stream>>>(q, k, v, Wq, Wk, Wv, bq, bk, bv,
                                          mask, mf, qp, q_bf, k_bf, vt);
  k_attn5<<<dim3(16, 32, 4), 256, 0, stream>>>(q_bf, k_bf, vt, mf, OpartB, LpartB);
  k_tail<<<256, 256, 0, stream>>>(qp, OpartB, LpartB, g1, b1, Wo, bo, g2, b2,
                                  (float*)d_out);
}